// Round 1
// baseline (1032.712 us; speedup 1.0000x reference)
//
#include <hip/hip_runtime.h>
#include <math.h>

// ---------------------------------------------------------------------------
// Problem constants (fixed by the reference).
// ---------------------------------------------------------------------------
namespace {

constexpr int kN0 = 100000, kN1 = 25000, kN2 = 6250;
constexpr int kE0 = 1600000, kE1 = 400000, kE2 = 100000;
// Concatenated-edge layout: [A0 | A1 | A2 | T0(assign0) | T1(assign1)]
constexpr int kEO1 = kE0;                   // 1,600,000
constexpr int kEO2 = kEO1 + kE1;            // 2,000,000
constexpr int kEO3 = kEO2 + kE2;            // 2,100,000
constexpr int kEO4 = kEO3 + kN0;            // 2,200,000
constexpr int kTE  = kEO4 + kN1;            // 2,225,000
// Concatenated-bin layout (destination node counts per graph)
constexpr int kBO1 = kN0;                   // 100,000  (A1 bins: N1)
constexpr int kBO2 = kBO1 + kN1;            // 125,000  (A2 bins: N2)
constexpr int kBO3 = kBO2 + kN2;            // 131,250  (T0 bins: N1)
constexpr int kBO4 = kBO3 + kN1;            // 156,250  (T1 bins: N2)
constexpr int kTB  = kBO4 + kN2;            // 162,500
constexpr int kNBLK = (kTB + 1023) / 1024;  // 159 scan blocks

// ---------------------------------------------------------------------------
// CSR build: histogram -> scan -> scatter (batched over all 5 graphs)
// ---------------------------------------------------------------------------
__global__ __launch_bounds__(256) void hist_kernel(
    const int* __restrict__ a0i, const int* __restrict__ a1i,
    const int* __restrict__ a2i, const int* __restrict__ as0,
    const int* __restrict__ as1, int* __restrict__ counts) {
  int t = blockIdx.x * 256 + threadIdx.x;
  if (t >= kTE) return;
  int dst, boff;
  if (t < kEO1)      { dst = a0i[t];        boff = 0;    }
  else if (t < kEO2) { dst = a1i[t - kEO1]; boff = kBO1; }
  else if (t < kEO3) { dst = a2i[t - kEO2]; boff = kBO2; }
  else if (t < kEO4) { dst = as0[t - kEO3]; boff = kBO3; }
  else               { dst = as1[t - kEO4]; boff = kBO4; }
  atomicAdd(&counts[boff + dst], 1);
}

__global__ __launch_bounds__(256) void scan1_kernel(
    const int* __restrict__ in, int* __restrict__ out,
    int* __restrict__ partials, int n) {
  __shared__ int sdata[256];
  int t = threadIdx.x;
  int base = blockIdx.x * 1024;
  int v[4]; int s = 0;
  #pragma unroll
  for (int j = 0; j < 4; ++j) {
    int i = base + t * 4 + j;
    v[j] = (i < n) ? in[i] : 0;
    s += v[j];
  }
  sdata[t] = s;
  __syncthreads();
  for (int off = 1; off < 256; off <<= 1) {
    int x = (t >= off) ? sdata[t - off] : 0;
    __syncthreads();
    sdata[t] += x;
    __syncthreads();
  }
  int excl = sdata[t] - s;  // exclusive prefix for this thread's first elem
  int run = 0;
  #pragma unroll
  for (int j = 0; j < 4; ++j) {
    int i = base + t * 4 + j;
    if (i < n) out[i] = excl + run;
    run += v[j];
  }
  if (t == 255) partials[blockIdx.x] = sdata[255];
}

__global__ __launch_bounds__(256) void scan2_kernel(int* partials, int nb) {
  __shared__ int sdata[256];
  int t = threadIdx.x;
  sdata[t] = (t < nb) ? partials[t] : 0;
  __syncthreads();
  for (int off = 1; off < 256; off <<= 1) {
    int x = (t >= off) ? sdata[t - off] : 0;
    __syncthreads();
    sdata[t] += x;
    __syncthreads();
  }
  if (t < nb) partials[t] = (t == 0) ? 0 : sdata[t - 1];
}

__global__ __launch_bounds__(256) void scan3_kernel(
    int* __restrict__ out, const int* __restrict__ partials, int n, int total) {
  int i = blockIdx.x * 256 + threadIdx.x;
  if (i < n) out[i] += partials[i >> 10];
  if (i == 0) out[n] = total;
}

__global__ __launch_bounds__(256) void scatter_kernel(
    const int* __restrict__ a0i, const float* __restrict__ a0v,
    const int* __restrict__ a1i, const int* __restrict__ a2i,
    const int* __restrict__ as0, const int* __restrict__ as1,
    int* __restrict__ next, int* __restrict__ ssrc, int* __restrict__ sdst,
    float* __restrict__ sval) {
  int t = blockIdx.x * 256 + threadIdx.x;
  if (t >= kTE) return;
  int dst, src, boff; float val;
  if (t < kEO1)      { dst = a0i[t]; src = a0i[kE0 + t]; val = a0v[t]; boff = 0; }
  else if (t < kEO2) { int e = t - kEO1; dst = a1i[e]; src = a1i[kE1 + e]; val = 1.0f; boff = kBO1; }
  else if (t < kEO3) { int e = t - kEO2; dst = a2i[e]; src = a2i[kE2 + e]; val = 1.0f; boff = kBO2; }
  else if (t < kEO4) { int e = t - kEO3; dst = as0[e]; src = e;            val = 1.0f; boff = kBO3; }
  else               { int e = t - kEO4; dst = as1[e]; src = e;            val = 1.0f; boff = kBO4; }
  int pos = atomicAdd(&next[boff + dst], 1);
  ssrc[pos] = src; sdst[pos] = dst; sval[pos] = val;
}

// ---------------------------------------------------------------------------
// Dense GEMMs (fp32 VALU). C[M,128] = A[M,128] @ W[128,128]
// Block: 256 threads, 64 rows. A tile in LDS (stride 132 kills bank
// conflicts: 8 rsub rows land on 8 distinct banks). W read from global
// (64 KB, L1/L2-resident across blocks).
// ---------------------------------------------------------------------------
__global__ __launch_bounds__(256) void gemm128_kernel(
    const float* __restrict__ A, const float* __restrict__ W,
    float* __restrict__ C, int M) {
  __shared__ float As[64 * 132];
  int t = threadIdx.x;
  int row0 = blockIdx.x << 6;
  #pragma unroll
  for (int i = 0; i < 8; ++i) {
    int f = t + (i << 8);
    int r = f >> 5, c4 = (f & 31) << 2;
    int gr = row0 + r;
    float4 v = make_float4(0.f, 0.f, 0.f, 0.f);
    if (gr < M) v = *(const float4*)&A[(size_t)gr * 128 + c4];
    *(float4*)&As[r * 132 + c4] = v;
  }
  __syncthreads();
  int wcol = t & 31;          // W float4 column group
  int c4 = wcol << 2;
  int rsub = t >> 5;          // 0..7
  float4 acc[8];
  #pragma unroll
  for (int j = 0; j < 8; ++j) acc[j] = make_float4(0.f, 0.f, 0.f, 0.f);
  const float4* W4 = (const float4*)W;
  #pragma unroll 4
  for (int k = 0; k < 128; ++k) {
    float4 w = W4[k * 32 + wcol];
    #pragma unroll
    for (int j = 0; j < 8; ++j) {
      float a = As[(rsub + (j << 3)) * 132 + k];
      acc[j].x = fmaf(a, w.x, acc[j].x);
      acc[j].y = fmaf(a, w.y, acc[j].y);
      acc[j].z = fmaf(a, w.z, acc[j].z);
      acc[j].w = fmaf(a, w.w, acc[j].w);
    }
  }
  #pragma unroll
  for (int j = 0; j < 8; ++j) {
    int gr = row0 + rsub + (j << 3);
    if (gr < M) *(float4*)&C[(size_t)gr * 128 + c4] = acc[j];
  }
}

// C[M,40] = A[M,128] @ W[128,40]
__global__ __launch_bounds__(256) void gemm40_kernel(
    const float* __restrict__ A, const float* __restrict__ W,
    float* __restrict__ C, int M) {
  __shared__ float Ws[128 * 40];
  __shared__ float As[64 * 132];
  int t = threadIdx.x;
  int row0 = blockIdx.x << 6;
  #pragma unroll
  for (int i = 0; i < 5; ++i)
    ((float4*)Ws)[t + i * 256] = ((const float4*)W)[t + i * 256];
  #pragma unroll
  for (int i = 0; i < 8; ++i) {
    int f = t + (i << 8);
    int r = f >> 5, c4 = (f & 31) << 2;
    int gr = row0 + r;
    float4 v = make_float4(0.f, 0.f, 0.f, 0.f);
    if (gr < M) v = *(const float4*)&A[(size_t)gr * 128 + c4];
    *(float4*)&As[r * 132 + c4] = v;
  }
  __syncthreads();
  int r = t >> 2;
  int cg = (t & 3) * 10;
  float acc[10];
  #pragma unroll
  for (int j = 0; j < 10; ++j) acc[j] = 0.f;
  for (int k = 0; k < 128; ++k) {
    float a = As[r * 132 + k];
    #pragma unroll
    for (int j = 0; j < 10; ++j) acc[j] = fmaf(a, Ws[k * 40 + cg + j], acc[j]);
  }
  int gr = row0 + r;
  if (gr < M) {
    #pragma unroll
    for (int j = 0; j < 10; ++j) C[(size_t)gr * 40 + cg + j] = acc[j];
  }
}

// ---------------------------------------------------------------------------
// Pull-SpMM over CSR: one wave per destination row, 128 cols as float2/lane.
// Edge metadata fetched coalesced in 64-chunks, broadcast via shfl.
// ---------------------------------------------------------------------------
__global__ __launch_bounds__(256) void spmm128_kernel(
    const int* __restrict__ row_ptr, const int* __restrict__ ssrc,
    const float* __restrict__ sval, const float* __restrict__ X,
    float* __restrict__ Y, const float* __restrict__ bias,
    int nrows, int do_relu) {
  int wid = (blockIdx.x * 256 + threadIdx.x) >> 6;
  int lane = threadIdx.x & 63;
  if (wid >= nrows) return;
  int start = row_ptr[wid], end = row_ptr[wid + 1];
  float2 acc = make_float2(0.f, 0.f);
  for (int base = start; base < end; base += 64) {
    int cnt = end - base; if (cnt > 64) cnt = 64;
    int s_l = 0; float v_l = 0.f;
    if (lane < cnt) { s_l = ssrc[base + lane]; v_l = sval[base + lane]; }
    for (int j = 0; j < cnt; ++j) {
      int src = __shfl(s_l, j);
      float val = __shfl(v_l, j);
      float2 xv = *(const float2*)&X[(size_t)src * 128 + lane * 2];
      acc.x = fmaf(val, xv.x, acc.x);
      acc.y = fmaf(val, xv.y, acc.y);
    }
  }
  if (bias) { acc.x += bias[lane * 2]; acc.y += bias[lane * 2 + 1]; }
  if (do_relu) { acc.x = fmaxf(acc.x, 0.f); acc.y = fmaxf(acc.y, 0.f); }
  *(float2*)&Y[(size_t)wid * 128 + lane * 2] = acc;
}

__global__ __launch_bounds__(256) void spmm40_kernel(
    const int* __restrict__ row_ptr, const int* __restrict__ ssrc,
    const float* __restrict__ sval, const float* __restrict__ X,
    float* __restrict__ Y, const float* __restrict__ bias, int nrows) {
  int wid = (blockIdx.x * 256 + threadIdx.x) >> 6;
  int lane = threadIdx.x & 63;
  if (wid >= nrows) return;
  int start = row_ptr[wid], end = row_ptr[wid + 1];
  float acc = 0.f;
  for (int base = start; base < end; base += 64) {
    int cnt = end - base; if (cnt > 64) cnt = 64;
    int s_l = 0; float v_l = 0.f;
    if (lane < cnt) { s_l = ssrc[base + lane]; v_l = sval[base + lane]; }
    for (int j = 0; j < cnt; ++j) {
      int src = __shfl(s_l, j);
      float val = __shfl(v_l, j);
      if (lane < 40) acc = fmaf(val, X[(size_t)src * 40 + lane], acc);
    }
  }
  if (lane < 40) Y[(size_t)wid * 40 + lane] = acc + bias[lane];
}

// ---------------------------------------------------------------------------
// CRF pieces
// ---------------------------------------------------------------------------
__global__ __launch_bounds__(256) void add_emb_kernel(
    const float* __restrict__ X, const int* __restrict__ nwgt,
    const float* __restrict__ emb, float* __restrict__ H0, int n) {
  int i = blockIdx.x * 256 + threadIdx.x;
  if (i >= n * 128) return;
  int r = i >> 7, c = i & 127;
  H0[i] = X[i] + emb[nwgt[r] * 128 + c];
}

// 32 lanes per sorted edge: logit = dot(q[dst], k[src]) / sqrt(128)
__global__ __launch_bounds__(256) void crf_logits_kernel(
    const int* __restrict__ ssrc, const int* __restrict__ sdst,
    const float* __restrict__ Q, const float* __restrict__ K,
    float* __restrict__ logits, int estart, int eend) {
  int gt = blockIdx.x * 256 + threadIdx.x;
  int e = estart + (gt >> 5);
  int l = threadIdx.x & 31;
  if (e >= eend) return;
  int dst = sdst[e], src = ssrc[e];
  float4 q = *(const float4*)&Q[(size_t)dst * 128 + l * 4];
  float4 k = *(const float4*)&K[(size_t)src * 128 + l * 4];
  float s = q.x * k.x + q.y * k.y + q.z * k.z + q.w * k.w;
  #pragma unroll
  for (int m = 16; m >= 1; m >>= 1) s += __shfl_xor(s, m);
  if (l == 0) logits[e] = s * 0.08838834764831845f;  // 1/sqrt(128)
}

// wave-per-row: segment softmax over stored logits + weighted h0 gather
__global__ __launch_bounds__(256) void crf_rows_kernel(
    const int* __restrict__ row_ptr, const int* __restrict__ ssrc,
    const float* __restrict__ logits, const float* __restrict__ H0,
    float* __restrict__ Y, const float* __restrict__ alpha_p,
    const float* __restrict__ beta_p, int nrows) {
  int wid = (blockIdx.x * 256 + threadIdx.x) >> 6;
  int lane = threadIdx.x & 63;
  if (wid >= nrows) return;
  int start = row_ptr[wid], end = row_ptr[wid + 1];
  float alpha = *alpha_p, beta = *beta_p;
  float m = -3.4e38f;
  for (int e = start; e < end; ++e) m = fmaxf(m, logits[e]);
  float z = 0.f;
  float2 msg = make_float2(0.f, 0.f);
  for (int e = start; e < end; ++e) {
    float w = __expf(logits[e] - m);
    z += w;
    int src = ssrc[e];
    float2 h = *(const float2*)&H0[(size_t)src * 128 + lane * 2];
    msg.x = fmaf(w, h.x, msg.x);
    msg.y = fmaf(w, h.y, msg.y);
  }
  float inv = 1.0f / (z + 1e-16f);
  float2 h0i = *(const float2*)&H0[(size_t)wid * 128 + lane * 2];
  float sc = 1.0f / (alpha + beta);
  float2 o;
  o.x = (alpha * h0i.x + beta * (msg.x * inv)) * sc;
  o.y = (alpha * h0i.y + beta * (msg.y * inv)) * sc;
  *(float2*)&Y[(size_t)wid * 128 + lane * 2] = o;
}

// Y[i] = Hup[assign[row(i)]] + Hskip[i]  (row-gather + skip add)
__global__ __launch_bounds__(256) void unpool_add_kernel(
    const float* __restrict__ Hup, const int* __restrict__ assign,
    const float* __restrict__ Hskip, float* __restrict__ Y, int n) {
  int i = blockIdx.x * 256 + threadIdx.x;
  if (i >= n * 128) return;
  int r = i >> 7, c = i & 127;
  Y[i] = Hup[(size_t)assign[r] * 128 + c] + Hskip[i];
}

}  // namespace

// ---------------------------------------------------------------------------
extern "C" void kernel_launch(void* const* d_in, const int* in_sizes, int n_in,
                              void* d_out, int out_size, void* d_ws, size_t ws_size,
                              hipStream_t stream) {
  const float* x       = (const float*)d_in[0];
  const int*   A0_idx  = (const int*)d_in[1];
  const float* A0_val  = (const float*)d_in[2];
  const int*   A1_idx  = (const int*)d_in[3];
  const int*   A2_idx  = (const int*)d_in[5];
  const int*   assign0 = (const int*)d_in[7];
  const int*   assign1 = (const int*)d_in[8];
  const int*   nwgt1   = (const int*)d_in[9];
  const int*   nwgt2   = (const int*)d_in[10];
  const float* gc1_W   = (const float*)d_in[11];
  const float* gc1_b   = (const float*)d_in[12];
  const float* gc2_W   = (const float*)d_in[13];
  const float* gc2_b   = (const float*)d_in[14];
  const float* c1_Wq   = (const float*)d_in[15];
  const float* c1_Wk   = (const float*)d_in[16];
  const float* c1_emb  = (const float*)d_in[17];
  const float* c1_al   = (const float*)d_in[18];
  const float* c1_be   = (const float*)d_in[19];
  const float* c2_Wq   = (const float*)d_in[20];
  const float* c2_Wk   = (const float*)d_in[21];
  const float* c2_emb  = (const float*)d_in[22];
  const float* c2_al   = (const float*)d_in[23];
  const float* c2_be   = (const float*)d_in[24];

  float* out_g = (float*)d_out;                      // [N0, 40]
  float* gcn_h = out_g + (size_t)kN0 * 40;           // [N0, 128]
  float* crf_h = gcn_h + (size_t)kN0 * 128;          // [N0, 128]

  // ---- workspace carving (manual reuse; total ~102 MB) ----
  char* ws = (char*)d_ws;
  size_t off = 0;
  auto carve = [&](size_t bytes) -> void* {
    void* p = ws + off;
    off += (bytes + 511) & ~(size_t)511;
    return p;
  };
  int*   counts   = (int*)carve((size_t)(kTB + 1) * 4);
  int*   row_ptr  = (int*)carve((size_t)(kTB + 1) * 4);
  int*   nxt      = (int*)carve((size_t)(kTB + 1) * 4);
  int*   partials = (int*)carve(1024);
  int*   ssrc     = (int*)carve((size_t)kTE * 4);
  int*   sdst     = (int*)carve((size_t)kTE * 4);
  float* sval     = (float*)carve((size_t)kTE * 4);
  float* logits   = (float*)carve((size_t)kTE * 4);
  float* h1_crf   = (float*)carve((size_t)kN1 * 128 * 4);  // live long
  char*  arena    = (char*)carve((size_t)kN0 * 128 * 4);   // 51.2 MB, reused
  // arena overlays (lifetimes verified against launch order below):
  float* xW      = (float*)(arena);                 // [launch 8 .. 9]
  float* h1_pool = (float*)(arena);                 // [10 .. 13]
  float* q1      = (float*)(arena + 12800000);      // [11 .. 14]
  float* k1      = (float*)(arena + 25600000);      // [12 .. 14]
  float* h0_1    = (float*)(arena + 38400000);      // [13 .. 15]
  float* h2_pool = (float*)(arena + 12800000);      // [16 .. 19]
  float* q2      = (float*)(arena + 16000000);      // [17 .. 20]
  float* k2      = (float*)(arena + 19200000);      // [18 .. 20]
  float* h0_2    = (float*)(arena + 22400000);      // [19 .. 21]
  float* h2_crf  = (float*)(arena + 25600000);      // [21 .. 22]
  float* u1      = (float*)(arena + 38400000);      // [22 .. 23]
  float* hW2     = (float*)(arena);                 // [24 .. 25]

  // ---- 1. batched CSR build for {A0, A1, A2, T0, T1} ----
  hipMemsetAsync(counts, 0, (size_t)(kTB + 1) * 4, stream);
  hist_kernel<<<(kTE + 255) / 256, 256, 0, stream>>>(A0_idx, A1_idx, A2_idx,
                                                     assign0, assign1, counts);
  scan1_kernel<<<kNBLK, 256, 0, stream>>>(counts, row_ptr, partials, kTB);
  scan2_kernel<<<1, 256, 0, stream>>>(partials, kNBLK);
  scan3_kernel<<<(kTB + 255) / 256, 256, 0, stream>>>(row_ptr, partials, kTB, kTE);
  hipMemcpyAsync(nxt, row_ptr, (size_t)(kTB + 1) * 4, hipMemcpyDeviceToDevice, stream);
  scatter_kernel<<<(kTE + 255) / 256, 256, 0, stream>>>(
      A0_idx, A0_val, A1_idx, A2_idx, assign0, assign1, nxt, ssrc, sdst, sval);

  // ---- 2. gc1: h = relu(A0 @ (x W1) + b1)  -> gcn_hidden (output) ----
  gemm128_kernel<<<(kN0 + 63) / 64, 256, 0, stream>>>(x, gc1_W, xW, kN0);          // 8
  spmm128_kernel<<<(kN0 + 3) / 4, 256, 0, stream>>>(row_ptr, ssrc, sval, xW,
                                                    gcn_h, gc1_b, kN0, 1);         // 9
  // ---- 3. level-1 pool + CRF ----
  spmm128_kernel<<<(kN1 + 3) / 4, 256, 0, stream>>>(row_ptr + kBO3, ssrc, sval,
                                                    gcn_h, h1_pool, nullptr, kN1, 0); // 10
  gemm128_kernel<<<(kN1 + 63) / 64, 256, 0, stream>>>(h1_pool, c1_Wq, q1, kN1);    // 11
  gemm128_kernel<<<(kN1 + 63) / 64, 256, 0, stream>>>(h1_pool, c1_Wk, k1, kN1);    // 12
  add_emb_kernel<<<(kN1 * 128 + 255) / 256, 256, 0, stream>>>(h1_pool, nwgt1,
                                                              c1_emb, h0_1, kN1);  // 13
  crf_logits_kernel<<<(kE1 * 32 + 255) / 256, 256, 0, stream>>>(ssrc, sdst, q1, k1,
                                                                logits, kEO1, kEO2); // 14
  crf_rows_kernel<<<(kN1 + 3) / 4, 256, 0, stream>>>(row_ptr + kBO1, ssrc, logits,
                                                     h0_1, h1_crf, c1_al, c1_be, kN1); // 15
  // ---- 4. level-2 pool + CRF ----
  spmm128_kernel<<<(kN2 + 3) / 4, 256, 0, stream>>>(row_ptr + kBO4, ssrc, sval,
                                                    h1_crf, h2_pool, nullptr, kN2, 0); // 16
  gemm128_kernel<<<(kN2 + 63) / 64, 256, 0, stream>>>(h2_pool, c2_Wq, q2, kN2);    // 17
  gemm128_kernel<<<(kN2 + 63) / 64, 256, 0, stream>>>(h2_pool, c2_Wk, k2, kN2);    // 18
  add_emb_kernel<<<(kN2 * 128 + 255) / 256, 256, 0, stream>>>(h2_pool, nwgt2,
                                                              c2_emb, h0_2, kN2);  // 19
  crf_logits_kernel<<<(kE2 * 32 + 255) / 256, 256, 0, stream>>>(ssrc, sdst, q2, k2,
                                                                logits, kEO2, kEO3); // 20
  crf_rows_kernel<<<(kN2 + 3) / 4, 256, 0, stream>>>(row_ptr + kBO2, ssrc, logits,
                                                     h0_2, h2_crf, c2_al, c2_be, kN2); // 21
  // ---- 5. unpool with skip connections -> crf_hidden (output) ----
  unpool_add_kernel<<<(kN1 * 128 + 255) / 256, 256, 0, stream>>>(h2_crf, assign1,
                                                                 h1_crf, u1, kN1); // 22
  unpool_add_kernel<<<(kN0 * 128 + 255) / 256, 256, 0, stream>>>(u1, assign0,
                                                                 gcn_h, crf_h, kN0); // 23
  // ---- 6. gc2: out = A0 @ (crf_hidden W2) + b2 ----
  gemm40_kernel<<<(kN0 + 63) / 64, 256, 0, stream>>>(crf_h, gc2_W, hW2, kN0);      // 24
  spmm40_kernel<<<(kN0 + 3) / 4, 256, 0, stream>>>(row_ptr, ssrc, sval, hW2,
                                                   out_g, gc2_b, kN0);             // 25
}

// Round 2
// 984.401 us; speedup vs baseline: 1.0491x; 1.0491x over previous
//
#include <hip/hip_runtime.h>
#include <hip/hip_bf16.h>
#include <math.h>

namespace {

constexpr int kN0 = 100000, kN1 = 25000, kN2 = 6250;
constexpr int kE0 = 1600000, kE1 = 400000, kE2 = 100000;
// Concatenated-edge layout: [A0 | A1 | A2 | T0(assign0) | T1(assign1)]
constexpr int kEO1 = kE0;                   // 1,600,000
constexpr int kEO2 = kEO1 + kE1;            // 2,000,000
constexpr int kEO3 = kEO2 + kE2;            // 2,100,000
constexpr int kEO4 = kEO3 + kN0;            // 2,200,000
constexpr int kTE  = kEO4 + kN1;            // 2,225,000
// Concatenated-bin layout (destination node counts per graph)
constexpr int kBO1 = kN0;                   // A1 bins
constexpr int kBO2 = kBO1 + kN1;            // A2 bins
constexpr int kBO3 = kBO2 + kN2;            // T0 bins
constexpr int kBO4 = kBO3 + kN1;            // T1 bins
constexpr int kTB  = kBO4 + kN2;            // 162,500
constexpr int kNBLK = (kTB + 1023) / 1024;  // 159 scan blocks

__device__ __forceinline__ float bf_lo(unsigned int u) {
  return __uint_as_float(u << 16);
}
__device__ __forceinline__ float bf_hi(unsigned int u) {
  return __uint_as_float(u & 0xffff0000u);
}
__device__ __forceinline__ unsigned short f2bf(float f) {
  __hip_bfloat16 h = __float2bfloat16(f);
  return *reinterpret_cast<unsigned short*>(&h);
}

// ---------------------------------------------------------------------------
// CSR build: histogram -> scan -> scatter (batched over all 5 graphs)
// ---------------------------------------------------------------------------
__global__ __launch_bounds__(256) void hist_kernel(
    const int* __restrict__ a0i, const int* __restrict__ a1i,
    const int* __restrict__ a2i, const int* __restrict__ as0,
    const int* __restrict__ as1, int* __restrict__ counts) {
  int t = blockIdx.x * 256 + threadIdx.x;
  if (t >= kTE) return;
  int dst, boff;
  if (t < kEO1)      { dst = a0i[t];        boff = 0;    }
  else if (t < kEO2) { dst = a1i[t - kEO1]; boff = kBO1; }
  else if (t < kEO3) { dst = a2i[t - kEO2]; boff = kBO2; }
  else if (t < kEO4) { dst = as0[t - kEO3]; boff = kBO3; }
  else               { dst = as1[t - kEO4]; boff = kBO4; }
  atomicAdd(&counts[boff + dst], 1);
}

__global__ __launch_bounds__(256) void scan1_kernel(
    const int* __restrict__ in, int* __restrict__ out,
    int* __restrict__ partials, int n) {
  __shared__ int sdata[256];
  int t = threadIdx.x;
  int base = blockIdx.x * 1024;
  int v[4]; int s = 0;
  #pragma unroll
  for (int j = 0; j < 4; ++j) {
    int i = base + t * 4 + j;
    v[j] = (i < n) ? in[i] : 0;
    s += v[j];
  }
  sdata[t] = s;
  __syncthreads();
  for (int off = 1; off < 256; off <<= 1) {
    int x = (t >= off) ? sdata[t - off] : 0;
    __syncthreads();
    sdata[t] += x;
    __syncthreads();
  }
  int excl = sdata[t] - s;
  int run = 0;
  #pragma unroll
  for (int j = 0; j < 4; ++j) {
    int i = base + t * 4 + j;
    if (i < n) out[i] = excl + run;
    run += v[j];
  }
  if (t == 255) partials[blockIdx.x] = sdata[255];
}

__global__ __launch_bounds__(256) void scan2_kernel(int* partials, int nb) {
  __shared__ int sdata[256];
  int t = threadIdx.x;
  sdata[t] = (t < nb) ? partials[t] : 0;
  __syncthreads();
  for (int off = 1; off < 256; off <<= 1) {
    int x = (t >= off) ? sdata[t - off] : 0;
    __syncthreads();
    sdata[t] += x;
    __syncthreads();
  }
  if (t < nb) partials[t] = (t == 0) ? 0 : sdata[t - 1];
}

__global__ __launch_bounds__(256) void scan3_kernel(
    int* __restrict__ out, const int* __restrict__ partials, int n, int total) {
  int i = blockIdx.x * 256 + threadIdx.x;
  if (i < n) out[i] += partials[i >> 10];
  if (i == 0) out[n] = total;
}

// Single int2 {src, val_bits} per edge: one 8B random store instead of 3x4B.
__global__ __launch_bounds__(256) void scatter_kernel(
    const int* __restrict__ a0i, const float* __restrict__ a0v,
    const int* __restrict__ a1i, const int* __restrict__ a2i,
    const int* __restrict__ as0, const int* __restrict__ as1,
    int* __restrict__ next, int2* __restrict__ edges) {
  int t = blockIdx.x * 256 + threadIdx.x;
  if (t >= kTE) return;
  int dst, src, boff; float val;
  if (t < kEO1)      { dst = a0i[t]; src = a0i[kE0 + t]; val = a0v[t]; boff = 0; }
  else if (t < kEO2) { int e = t - kEO1; dst = a1i[e]; src = a1i[kE1 + e]; val = 1.0f; boff = kBO1; }
  else if (t < kEO3) { int e = t - kEO2; dst = a2i[e]; src = a2i[kE2 + e]; val = 1.0f; boff = kBO2; }
  else if (t < kEO4) { int e = t - kEO3; dst = as0[e]; src = e;            val = 1.0f; boff = kBO3; }
  else               { int e = t - kEO4; dst = as1[e]; src = e;            val = 1.0f; boff = kBO4; }
  int pos = atomicAdd(&next[boff + dst], 1);
  edges[pos] = make_int2(src, __float_as_int(val));
}

// ---------------------------------------------------------------------------
// GEMM C[M,128] = A[M,128] @ W[128,128]; optional fp32 and/or bf16 outputs.
// ---------------------------------------------------------------------------
__global__ __launch_bounds__(256) void gemm128_kernel(
    const float* __restrict__ A, const float* __restrict__ W,
    float* __restrict__ Cf, unsigned short* __restrict__ Cb, int M) {
  __shared__ float As[64 * 132];
  int t = threadIdx.x;
  int row0 = blockIdx.x << 6;
  #pragma unroll
  for (int i = 0; i < 8; ++i) {
    int f = t + (i << 8);
    int r = f >> 5, c4 = (f & 31) << 2;
    int gr = row0 + r;
    float4 v = make_float4(0.f, 0.f, 0.f, 0.f);
    if (gr < M) v = *(const float4*)&A[(size_t)gr * 128 + c4];
    *(float4*)&As[r * 132 + c4] = v;
  }
  __syncthreads();
  int wcol = t & 31;
  int c4 = wcol << 2;
  int rsub = t >> 5;
  float4 acc[8];
  #pragma unroll
  for (int j = 0; j < 8; ++j) acc[j] = make_float4(0.f, 0.f, 0.f, 0.f);
  const float4* W4 = (const float4*)W;
  #pragma unroll 4
  for (int k = 0; k < 128; ++k) {
    float4 w = W4[k * 32 + wcol];
    #pragma unroll
    for (int j = 0; j < 8; ++j) {
      float a = As[(rsub + (j << 3)) * 132 + k];
      acc[j].x = fmaf(a, w.x, acc[j].x);
      acc[j].y = fmaf(a, w.y, acc[j].y);
      acc[j].z = fmaf(a, w.z, acc[j].z);
      acc[j].w = fmaf(a, w.w, acc[j].w);
    }
  }
  #pragma unroll
  for (int j = 0; j < 8; ++j) {
    int gr = row0 + rsub + (j << 3);
    if (gr < M) {
      if (Cf) *(float4*)&Cf[(size_t)gr * 128 + c4] = acc[j];
      if (Cb) {
        ushort4 b;
        b.x = f2bf(acc[j].x); b.y = f2bf(acc[j].y);
        b.z = f2bf(acc[j].z); b.w = f2bf(acc[j].w);
        *(ushort4*)&Cb[(size_t)gr * 128 + c4] = b;
      }
    }
  }
}

// C[M,40] = A[M,128] @ W[128,40], bf16 output (consumed by gathers only)
__global__ __launch_bounds__(256) void gemm40_kernel(
    const float* __restrict__ A, const float* __restrict__ W,
    unsigned short* __restrict__ Cb, int M) {
  __shared__ float Ws[128 * 40];
  __shared__ float As[64 * 132];
  int t = threadIdx.x;
  int row0 = blockIdx.x << 6;
  #pragma unroll
  for (int i = 0; i < 5; ++i)
    ((float4*)Ws)[t + i * 256] = ((const float4*)W)[t + i * 256];
  #pragma unroll
  for (int i = 0; i < 8; ++i) {
    int f = t + (i << 8);
    int r = f >> 5, c4 = (f & 31) << 2;
    int gr = row0 + r;
    float4 v = make_float4(0.f, 0.f, 0.f, 0.f);
    if (gr < M) v = *(const float4*)&A[(size_t)gr * 128 + c4];
    *(float4*)&As[r * 132 + c4] = v;
  }
  __syncthreads();
  int r = t >> 2;
  int cg = (t & 3) * 10;
  float acc[10];
  #pragma unroll
  for (int j = 0; j < 10; ++j) acc[j] = 0.f;
  for (int k = 0; k < 128; ++k) {
    float a = As[r * 132 + k];
    #pragma unroll
    for (int j = 0; j < 10; ++j) acc[j] = fmaf(a, Ws[k * 40 + cg + j], acc[j]);
  }
  int gr = row0 + r;
  if (gr < M) {
    #pragma unroll
    for (int j = 0; j < 10; ++j) Cb[(size_t)gr * 40 + cg + j] = f2bf(acc[j]);
  }
}

// ---------------------------------------------------------------------------
// Pull-SpMM over CSR: one wave per dst row, 128 cols (2/lane).
// BF16 variant gathers bf16 rows (4B/lane), fp32 accumulate.
// ---------------------------------------------------------------------------
template <bool BF16>
__global__ __launch_bounds__(256) void spmm128_kernel(
    const int* __restrict__ row_ptr, const int2* __restrict__ edges,
    const void* __restrict__ Xv, float* __restrict__ Y,
    const float* __restrict__ bias, int nrows, int do_relu) {
  int wid = (blockIdx.x * 256 + threadIdx.x) >> 6;
  int lane = threadIdx.x & 63;
  if (wid >= nrows) return;
  int start = row_ptr[wid], end = row_ptr[wid + 1];
  float2 acc = make_float2(0.f, 0.f);
  for (int base = start; base < end; base += 64) {
    int cnt = end - base; if (cnt > 64) cnt = 64;
    int2 e_l = make_int2(0, 0);
    if (lane < cnt) e_l = edges[base + lane];
    for (int j = 0; j < cnt; ++j) {
      int src = __shfl(e_l.x, j);
      float val = __int_as_float(__shfl(e_l.y, j));
      float2 xv;
      if (BF16) {
        unsigned int u = *(const unsigned int*)
            ((const unsigned short*)Xv + (size_t)src * 128 + lane * 2);
        xv = make_float2(bf_lo(u), bf_hi(u));
      } else {
        xv = *(const float2*)((const float*)Xv + (size_t)src * 128 + lane * 2);
      }
      acc.x = fmaf(val, xv.x, acc.x);
      acc.y = fmaf(val, xv.y, acc.y);
    }
  }
  if (bias) { acc.x += bias[lane * 2]; acc.y += bias[lane * 2 + 1]; }
  if (do_relu) { acc.x = fmaxf(acc.x, 0.f); acc.y = fmaxf(acc.y, 0.f); }
  *(float2*)&Y[(size_t)wid * 128 + lane * 2] = acc;
}

__global__ __launch_bounds__(256) void spmm40_kernel(
    const int* __restrict__ row_ptr, const int2* __restrict__ edges,
    const unsigned short* __restrict__ Xb, float* __restrict__ Y,
    const float* __restrict__ bias, int nrows) {
  int wid = (blockIdx.x * 256 + threadIdx.x) >> 6;
  int lane = threadIdx.x & 63;
  if (wid >= nrows) return;
  int start = row_ptr[wid], end = row_ptr[wid + 1];
  float acc = 0.f;
  for (int base = start; base < end; base += 64) {
    int cnt = end - base; if (cnt > 64) cnt = 64;
    int2 e_l = make_int2(0, 0);
    if (lane < cnt) e_l = edges[base + lane];
    for (int j = 0; j < cnt; ++j) {
      int src = __shfl(e_l.x, j);
      float val = __int_as_float(__shfl(e_l.y, j));
      if (lane < 40) {
        unsigned short u = Xb[(size_t)src * 40 + lane];
        acc = fmaf(val, __uint_as_float(((unsigned int)u) << 16), acc);
      }
    }
  }
  if (lane < 40) Y[(size_t)wid * 40 + lane] = acc + bias[lane];
}

// ---------------------------------------------------------------------------
// CRF pieces
// ---------------------------------------------------------------------------
__global__ __launch_bounds__(256) void add_emb_kernel(
    const float* __restrict__ X, const int* __restrict__ nwgt,
    const float* __restrict__ emb, float* __restrict__ H0,
    unsigned short* __restrict__ H0b, int n) {
  int i = blockIdx.x * 256 + threadIdx.x;
  if (i >= n * 128) return;
  int r = i >> 7, c = i & 127;
  float v = X[i] + emb[nwgt[r] * 128 + c];
  H0[i] = v;
  H0b[i] = f2bf(v);
}

// Fused CRF row kernel: wave per dst row; q[row] in registers; per edge
// gather k[src] (bf16), butterfly dot -> logit; online-softmax rescale of
// the running (z, msg) with h0[src] (bf16) gathered in the same pass.
__global__ __launch_bounds__(256) void crf_fused_kernel(
    const int* __restrict__ row_ptr, const int2* __restrict__ edges,
    const float* __restrict__ Q, const unsigned short* __restrict__ Kb,
    const float* __restrict__ H0, const unsigned short* __restrict__ H0b,
    float* __restrict__ Y, const float* __restrict__ alpha_p,
    const float* __restrict__ beta_p, int nrows) {
  int wid = (blockIdx.x * 256 + threadIdx.x) >> 6;
  int lane = threadIdx.x & 63;
  if (wid >= nrows) return;
  int start = row_ptr[wid], end = row_ptr[wid + 1];
  float2 qv = *(const float2*)&Q[(size_t)wid * 128 + lane * 2];
  float m = -3.4e38f, z = 0.f;
  float2 msg = make_float2(0.f, 0.f);
  for (int e = start; e < end; ++e) {
    int src = edges[e].x;
    unsigned int ku = *(const unsigned int*)(Kb + (size_t)src * 128 + lane * 2);
    float p = qv.x * bf_lo(ku) + qv.y * bf_hi(ku);
    #pragma unroll
    for (int d = 32; d >= 1; d >>= 1) p += __shfl_xor(p, d);
    p *= 0.08838834764831845f;  // 1/sqrt(128); identical across lanes
    float mn = fmaxf(m, p);
    float corr = __expf(m - mn);   // 0 when m==-inf (first edge)
    float w = __expf(p - mn);
    z = z * corr + w;
    unsigned int hu = *(const unsigned int*)(H0b + (size_t)src * 128 + lane * 2);
    msg.x = msg.x * corr + w * bf_lo(hu);
    msg.y = msg.y * corr + w * bf_hi(hu);
    m = mn;
  }
  float alpha = *alpha_p, beta = *beta_p;
  float inv = 1.0f / (z + 1e-16f);
  float2 h0i = *(const float2*)&H0[(size_t)wid * 128 + lane * 2];
  float sc = 1.0f / (alpha + beta);
  float2 o;
  o.x = (alpha * h0i.x + beta * (msg.x * inv)) * sc;
  o.y = (alpha * h0i.y + beta * (msg.y * inv)) * sc;
  *(float2*)&Y[(size_t)wid * 128 + lane * 2] = o;
}

__global__ __launch_bounds__(256) void unpool_add_kernel(
    const float* __restrict__ Hup, const int* __restrict__ assign,
    const float* __restrict__ Hskip, float* __restrict__ Y, int n) {
  int i = blockIdx.x * 256 + threadIdx.x;
  if (i >= n * 128) return;
  int r = i >> 7, c = i & 127;
  Y[i] = Hup[(size_t)assign[r] * 128 + c] + Hskip[i];
}

}  // namespace

// ---------------------------------------------------------------------------
extern "C" void kernel_launch(void* const* d_in, const int* in_sizes, int n_in,
                              void* d_out, int out_size, void* d_ws, size_t ws_size,
                              hipStream_t stream) {
  const float* x       = (const float*)d_in[0];
  const int*   A0_idx  = (const int*)d_in[1];
  const float* A0_val  = (const float*)d_in[2];
  const int*   A1_idx  = (const int*)d_in[3];
  const int*   A2_idx  = (const int*)d_in[5];
  const int*   assign0 = (const int*)d_in[7];
  const int*   assign1 = (const int*)d_in[8];
  const int*   nwgt1   = (const int*)d_in[9];
  const int*   nwgt2   = (const int*)d_in[10];
  const float* gc1_W   = (const float*)d_in[11];
  const float* gc1_b   = (const float*)d_in[12];
  const float* gc2_W   = (const float*)d_in[13];
  const float* gc2_b   = (const float*)d_in[14];
  const float* c1_Wq   = (const float*)d_in[15];
  const float* c1_Wk   = (const float*)d_in[16];
  const float* c1_emb  = (const float*)d_in[17];
  const float* c1_al   = (const float*)d_in[18];
  const float* c1_be   = (const float*)d_in[19];
  const float* c2_Wq   = (const float*)d_in[20];
  const float* c2_Wk   = (const float*)d_in[21];
  const float* c2_emb  = (const float*)d_in[22];
  const float* c2_al   = (const float*)d_in[23];
  const float* c2_be   = (const float*)d_in[24];

  float* out_g = (float*)d_out;                      // [N0, 40]
  float* gcn_h = out_g + (size_t)kN0 * 40;           // [N0, 128]
  float* crf_h = gcn_h + (size_t)kN0 * 128;          // [N0, 128]

  // ---- workspace carving ----
  char* ws = (char*)d_ws;
  size_t off = 0;
  auto carve = [&](size_t bytes) -> void* {
    void* p = ws + off;
    off += (bytes + 511) & ~(size_t)511;
    return p;
  };
  int*   counts   = (int*)carve((size_t)(kTB + 1) * 4);
  int*   row_ptr  = (int*)carve((size_t)(kTB + 1) * 4);
  int*   nxt      = (int*)carve((size_t)(kTB + 1) * 4);
  int*   partials = (int*)carve(1024);
  int2*  edges    = (int2*)carve((size_t)kTE * 8);         // 17.8 MB
  float* h1_crf   = (float*)carve((size_t)kN1 * 128 * 4);  // 12.8 MB, long-lived
  char*  arena    = (char*)carve(51200000 + 4096);         // reused overlays
  // Overlays (byte offsets; lifetimes checked against launch order):
  unsigned short* xWb   = (unsigned short*)(arena);              // gc1 [8..9]
  float* h1_pool = (float*)(arena);                              // [10..13]
  float* q1      = (float*)(arena + 12800000);                   // [11..15]
  unsigned short* k1b   = (unsigned short*)(arena + 25600000);   // [12..15]
  float* h0_1    = (float*)(arena + 32000000);                   // [13..15]
  unsigned short* h0_1b = (unsigned short*)(arena + 44800000);   // [13..15]
  float* h2_pool = (float*)(arena);                              // [16..19]
  float* q2      = (float*)(arena + 3200000);                    // [17..21]
  unsigned short* k2b   = (unsigned short*)(arena + 6400000);    // [18..21]
  float* h0_2    = (float*)(arena + 8000000);                    // [19..21]
  unsigned short* h0_2b = (unsigned short*)(arena + 11200000);   // [19..21]
  float* h2_crf  = (float*)(arena + 12800000);                   // [21..22]
  float* u1      = (float*)(arena + 16000000);                   // [22..23]
  unsigned short* hW2b  = (unsigned short*)(arena);              // [24..25]

  // ---- 1. batched CSR build for {A0, A1, A2, T0, T1} ----
  hipMemsetAsync(counts, 0, (size_t)(kTB + 1) * 4, stream);
  hist_kernel<<<(kTE + 255) / 256, 256, 0, stream>>>(A0_idx, A1_idx, A2_idx,
                                                     assign0, assign1, counts);
  scan1_kernel<<<kNBLK, 256, 0, stream>>>(counts, row_ptr, partials, kTB);
  scan2_kernel<<<1, 256, 0, stream>>>(partials, kNBLK);
  scan3_kernel<<<(kTB + 255) / 256, 256, 0, stream>>>(row_ptr, partials, kTB, kTE);
  hipMemcpyAsync(nxt, row_ptr, (size_t)(kTB + 1) * 4, hipMemcpyDeviceToDevice, stream);
  scatter_kernel<<<(kTE + 255) / 256, 256, 0, stream>>>(
      A0_idx, A0_val, A1_idx, A2_idx, assign0, assign1, nxt, edges);

  // ---- 2. gc1: h = relu(A0 @ (x W1) + b1) -> gcn_hidden ----
  gemm128_kernel<<<(kN0 + 63) / 64, 256, 0, stream>>>(x, gc1_W, nullptr, xWb, kN0);  // 8
  spmm128_kernel<true><<<(kN0 + 3) / 4, 256, 0, stream>>>(row_ptr, edges, xWb,
                                                          gcn_h, gc1_b, kN0, 1);     // 9
  // ---- 3. level-1 pool + CRF ----
  spmm128_kernel<false><<<(kN1 + 3) / 4, 256, 0, stream>>>(row_ptr + kBO3, edges,
                                                           gcn_h, h1_pool, nullptr, kN1, 0); // 10
  gemm128_kernel<<<(kN1 + 63) / 64, 256, 0, stream>>>(h1_pool, c1_Wq, q1, nullptr, kN1);     // 11
  gemm128_kernel<<<(kN1 + 63) / 64, 256, 0, stream>>>(h1_pool, c1_Wk, nullptr, k1b, kN1);    // 12
  add_emb_kernel<<<(kN1 * 128 + 255) / 256, 256, 0, stream>>>(h1_pool, nwgt1, c1_emb,
                                                              h0_1, h0_1b, kN1);             // 13
  crf_fused_kernel<<<(kN1 + 3) / 4, 256, 0, stream>>>(row_ptr + kBO1, edges, q1, k1b,
                                                      h0_1, h0_1b, h1_crf, c1_al, c1_be, kN1); // 15
  // ---- 4. level-2 pool + CRF ----
  spmm128_kernel<false><<<(kN2 + 3) / 4, 256, 0, stream>>>(row_ptr + kBO4, edges,
                                                           h1_crf, h2_pool, nullptr, kN2, 0); // 16
  gemm128_kernel<<<(kN2 + 63) / 64, 256, 0, stream>>>(h2_pool, c2_Wq, q2, nullptr, kN2);      // 17
  gemm128_kernel<<<(kN2 + 63) / 64, 256, 0, stream>>>(h2_pool, c2_Wk, nullptr, k2b, kN2);     // 18
  add_emb_kernel<<<(kN2 * 128 + 255) / 256, 256, 0, stream>>>(h2_pool, nwgt2, c2_emb,
                                                              h0_2, h0_2b, kN2);              // 19
  crf_fused_kernel<<<(kN2 + 3) / 4, 256, 0, stream>>>(row_ptr + kBO2, edges, q2, k2b,
                                                      h0_2, h0_2b, h2_crf, c2_al, c2_be, kN2); // 21
  // ---- 5. unpool with skip connections -> crf_hidden ----
  unpool_add_kernel<<<(kN1 * 128 + 255) / 256, 256, 0, stream>>>(h2_crf, assign1,
                                                                 h1_crf, u1, kN1);            // 22
  unpool_add_kernel<<<(kN0 * 128 + 255) / 256, 256, 0, stream>>>(u1, assign0,
                                                                 gcn_h, crf_h, kN0);          // 23
  // ---- 6. gc2: out = A0 @ (crf_hidden W2) + b2 ----
  gemm40_kernel<<<(kN0 + 63) / 64, 256, 0, stream>>>(crf_h, gc2_W, hW2b, kN0);                // 24
  spmm40_kernel<<<(kN0 + 3) / 4, 256, 0, stream>>>(row_ptr, edges, hW2b,
                                                   out_g, gc2_b, kN0);                        // 25
}

// Round 3
// 851.072 us; speedup vs baseline: 1.2134x; 1.1567x over previous
//
#include <hip/hip_runtime.h>
#include <hip/hip_bf16.h>
#include <math.h>

namespace {

constexpr int kN0 = 100000, kN1 = 25000, kN2 = 6250;
constexpr int kE0 = 1600000, kE1 = 400000, kE2 = 100000;
// Concatenated-edge layout: [A0 | A1 | A2 | T0(assign0) | T1(assign1)]
constexpr int kEO1 = kE0;                   // 1,600,000
constexpr int kEO2 = kEO1 + kE1;            // 2,000,000
constexpr int kEO3 = kEO2 + kE2;            // 2,100,000
constexpr int kEO4 = kEO3 + kN0;            // 2,200,000
constexpr int kTE  = kEO4 + kN1;            // 2,225,000
// Concatenated-bin layout (destination node counts per graph)
constexpr int kBO1 = kN0;                   // A1 bins
constexpr int kBO2 = kBO1 + kN1;            // A2 bins
constexpr int kBO3 = kBO2 + kN2;            // T0 bins
constexpr int kBO4 = kBO3 + kN1;            // T1 bins
constexpr int kTB  = kBO4 + kN2;            // 162,500
constexpr int kNBLK = (kTB + 1023) / 1024;  // 159 scan blocks

__device__ __forceinline__ float bf_lo(unsigned int u) {
  return __uint_as_float(u << 16);
}
__device__ __forceinline__ float bf_hi(unsigned int u) {
  return __uint_as_float(u & 0xffff0000u);
}
__device__ __forceinline__ unsigned short f2bf(float f) {
  __hip_bfloat16 h = __float2bfloat16(f);
  return *reinterpret_cast<unsigned short*>(&h);
}

// ---------------------------------------------------------------------------
// CSR build, atomic-light: rank (1 atomic pass) -> scan -> place (no atomics)
// ---------------------------------------------------------------------------
__global__ __launch_bounds__(256) void rank_kernel(
    const int* __restrict__ a0i, const int* __restrict__ a1i,
    const int* __restrict__ a2i, const int* __restrict__ as0,
    const int* __restrict__ as1, int* __restrict__ counts,
    int* __restrict__ rank) {
  int t = blockIdx.x * 256 + threadIdx.x;
  if (t >= kTE) return;
  int dst, boff;
  if (t < kEO1)      { dst = a0i[t];        boff = 0;    }
  else if (t < kEO2) { dst = a1i[t - kEO1]; boff = kBO1; }
  else if (t < kEO3) { dst = a2i[t - kEO2]; boff = kBO2; }
  else if (t < kEO4) { dst = as0[t - kEO3]; boff = kBO3; }
  else               { dst = as1[t - kEO4]; boff = kBO4; }
  rank[t] = atomicAdd(&counts[boff + dst], 1);
}

__global__ __launch_bounds__(256) void scan1_kernel(
    const int* __restrict__ in, int* __restrict__ out,
    int* __restrict__ partials, int n) {
  __shared__ int sdata[256];
  int t = threadIdx.x;
  int base = blockIdx.x * 1024;
  int v[4]; int s = 0;
  #pragma unroll
  for (int j = 0; j < 4; ++j) {
    int i = base + t * 4 + j;
    v[j] = (i < n) ? in[i] : 0;
    s += v[j];
  }
  sdata[t] = s;
  __syncthreads();
  for (int off = 1; off < 256; off <<= 1) {
    int x = (t >= off) ? sdata[t - off] : 0;
    __syncthreads();
    sdata[t] += x;
    __syncthreads();
  }
  int excl = sdata[t] - s;
  int run = 0;
  #pragma unroll
  for (int j = 0; j < 4; ++j) {
    int i = base + t * 4 + j;
    if (i < n) out[i] = excl + run;
    run += v[j];
  }
  if (t == 255) partials[blockIdx.x] = sdata[255];
}

__global__ __launch_bounds__(256) void scan2_kernel(int* partials, int nb) {
  __shared__ int sdata[256];
  int t = threadIdx.x;
  sdata[t] = (t < nb) ? partials[t] : 0;
  __syncthreads();
  for (int off = 1; off < 256; off <<= 1) {
    int x = (t >= off) ? sdata[t - off] : 0;
    __syncthreads();
    sdata[t] += x;
    __syncthreads();
  }
  if (t < nb) partials[t] = (t == 0) ? 0 : sdata[t - 1];
}

__global__ __launch_bounds__(256) void scan3_kernel(
    int* __restrict__ out, const int* __restrict__ partials, int n, int total) {
  int i = blockIdx.x * 256 + threadIdx.x;
  if (i < n) out[i] += partials[i >> 10];
  if (i == 0) out[n] = total;
}

// No atomics: pos = row_ptr[bin] + rank[t]; one random 8B store per edge.
__global__ __launch_bounds__(256) void place_kernel(
    const int* __restrict__ a0i, const float* __restrict__ a0v,
    const int* __restrict__ a1i, const int* __restrict__ a2i,
    const int* __restrict__ as0, const int* __restrict__ as1,
    const int* __restrict__ row_ptr, const int* __restrict__ rank,
    int2* __restrict__ edges) {
  int t = blockIdx.x * 256 + threadIdx.x;
  if (t >= kTE) return;
  int dst, src, boff; float val;
  if (t < kEO1)      { dst = a0i[t]; src = a0i[kE0 + t]; val = a0v[t]; boff = 0; }
  else if (t < kEO2) { int e = t - kEO1; dst = a1i[e]; src = a1i[kE1 + e]; val = 1.0f; boff = kBO1; }
  else if (t < kEO3) { int e = t - kEO2; dst = a2i[e]; src = a2i[kE2 + e]; val = 1.0f; boff = kBO2; }
  else if (t < kEO4) { int e = t - kEO3; dst = as0[e]; src = e;            val = 1.0f; boff = kBO3; }
  else               { int e = t - kEO4; dst = as1[e]; src = e;            val = 1.0f; boff = kBO4; }
  int pos = row_ptr[boff + dst] + rank[t];
  edges[pos] = make_int2(src, __float_as_int(val));
}

// ---------------------------------------------------------------------------
// GEMM C[M,128] = A[M,128] @ W[128,128]; optional fp32 and/or bf16 outputs.
// ---------------------------------------------------------------------------
__global__ __launch_bounds__(256) void gemm128_kernel(
    const float* __restrict__ A, const float* __restrict__ W,
    float* __restrict__ Cf, unsigned short* __restrict__ Cb, int M) {
  __shared__ float As[64 * 132];
  int t = threadIdx.x;
  int row0 = blockIdx.x << 6;
  #pragma unroll
  for (int i = 0; i < 8; ++i) {
    int f = t + (i << 8);
    int r = f >> 5, c4 = (f & 31) << 2;
    int gr = row0 + r;
    float4 v = make_float4(0.f, 0.f, 0.f, 0.f);
    if (gr < M) v = *(const float4*)&A[(size_t)gr * 128 + c4];
    *(float4*)&As[r * 132 + c4] = v;
  }
  __syncthreads();
  int wcol = t & 31;
  int c4 = wcol << 2;
  int rsub = t >> 5;
  float4 acc[8];
  #pragma unroll
  for (int j = 0; j < 8; ++j) acc[j] = make_float4(0.f, 0.f, 0.f, 0.f);
  const float4* W4 = (const float4*)W;
  #pragma unroll 4
  for (int k = 0; k < 128; ++k) {
    float4 w = W4[k * 32 + wcol];
    #pragma unroll
    for (int j = 0; j < 8; ++j) {
      float a = As[(rsub + (j << 3)) * 132 + k];
      acc[j].x = fmaf(a, w.x, acc[j].x);
      acc[j].y = fmaf(a, w.y, acc[j].y);
      acc[j].z = fmaf(a, w.z, acc[j].z);
      acc[j].w = fmaf(a, w.w, acc[j].w);
    }
  }
  #pragma unroll
  for (int j = 0; j < 8; ++j) {
    int gr = row0 + rsub + (j << 3);
    if (gr < M) {
      if (Cf) *(float4*)&Cf[(size_t)gr * 128 + c4] = acc[j];
      if (Cb) {
        ushort4 b;
        b.x = f2bf(acc[j].x); b.y = f2bf(acc[j].y);
        b.z = f2bf(acc[j].z); b.w = f2bf(acc[j].w);
        *(ushort4*)&Cb[(size_t)gr * 128 + c4] = b;
      }
    }
  }
}

// Fused Q/K projection: one LDS tile of A, two K-loops (Wq -> fp32, Wk -> bf16).
__global__ __launch_bounds__(256) void gemm128_qk_kernel(
    const float* __restrict__ A, const float* __restrict__ Wq,
    const float* __restrict__ Wk, float* __restrict__ Qf,
    unsigned short* __restrict__ Kb, int M) {
  __shared__ float As[64 * 132];
  int t = threadIdx.x;
  int row0 = blockIdx.x << 6;
  #pragma unroll
  for (int i = 0; i < 8; ++i) {
    int f = t + (i << 8);
    int r = f >> 5, c4 = (f & 31) << 2;
    int gr = row0 + r;
    float4 v = make_float4(0.f, 0.f, 0.f, 0.f);
    if (gr < M) v = *(const float4*)&A[(size_t)gr * 128 + c4];
    *(float4*)&As[r * 132 + c4] = v;
  }
  __syncthreads();
  int wcol = t & 31;
  int c4 = wcol << 2;
  int rsub = t >> 5;
  float4 acc[8];
  const float4* Wq4 = (const float4*)Wq;
  const float4* Wk4 = (const float4*)Wk;
  // pass 1: Q (fp32 out)
  #pragma unroll
  for (int j = 0; j < 8; ++j) acc[j] = make_float4(0.f, 0.f, 0.f, 0.f);
  #pragma unroll 4
  for (int k = 0; k < 128; ++k) {
    float4 w = Wq4[k * 32 + wcol];
    #pragma unroll
    for (int j = 0; j < 8; ++j) {
      float a = As[(rsub + (j << 3)) * 132 + k];
      acc[j].x = fmaf(a, w.x, acc[j].x);
      acc[j].y = fmaf(a, w.y, acc[j].y);
      acc[j].z = fmaf(a, w.z, acc[j].z);
      acc[j].w = fmaf(a, w.w, acc[j].w);
    }
  }
  #pragma unroll
  for (int j = 0; j < 8; ++j) {
    int gr = row0 + rsub + (j << 3);
    if (gr < M) *(float4*)&Qf[(size_t)gr * 128 + c4] = acc[j];
  }
  // pass 2: K (bf16 out)
  #pragma unroll
  for (int j = 0; j < 8; ++j) acc[j] = make_float4(0.f, 0.f, 0.f, 0.f);
  #pragma unroll 4
  for (int k = 0; k < 128; ++k) {
    float4 w = Wk4[k * 32 + wcol];
    #pragma unroll
    for (int j = 0; j < 8; ++j) {
      float a = As[(rsub + (j << 3)) * 132 + k];
      acc[j].x = fmaf(a, w.x, acc[j].x);
      acc[j].y = fmaf(a, w.y, acc[j].y);
      acc[j].z = fmaf(a, w.z, acc[j].z);
      acc[j].w = fmaf(a, w.w, acc[j].w);
    }
  }
  #pragma unroll
  for (int j = 0; j < 8; ++j) {
    int gr = row0 + rsub + (j << 3);
    if (gr < M) {
      ushort4 b;
      b.x = f2bf(acc[j].x); b.y = f2bf(acc[j].y);
      b.z = f2bf(acc[j].z); b.w = f2bf(acc[j].w);
      *(ushort4*)&Kb[(size_t)gr * 128 + c4] = b;
    }
  }
}

// C[M,40] = A[M,128] @ W[128,40], bf16 output (consumed by gathers only)
__global__ __launch_bounds__(256) void gemm40_kernel(
    const float* __restrict__ A, const float* __restrict__ W,
    unsigned short* __restrict__ Cb, int M) {
  __shared__ float Ws[128 * 40];
  __shared__ float As[64 * 132];
  int t = threadIdx.x;
  int row0 = blockIdx.x << 6;
  #pragma unroll
  for (int i = 0; i < 5; ++i)
    ((float4*)Ws)[t + i * 256] = ((const float4*)W)[t + i * 256];
  #pragma unroll
  for (int i = 0; i < 8; ++i) {
    int f = t + (i << 8);
    int r = f >> 5, c4 = (f & 31) << 2;
    int gr = row0 + r;
    float4 v = make_float4(0.f, 0.f, 0.f, 0.f);
    if (gr < M) v = *(const float4*)&A[(size_t)gr * 128 + c4];
    *(float4*)&As[r * 132 + c4] = v;
  }
  __syncthreads();
  int r = t >> 2;
  int cg = (t & 3) * 10;
  float acc[10];
  #pragma unroll
  for (int j = 0; j < 10; ++j) acc[j] = 0.f;
  for (int k = 0; k < 128; ++k) {
    float a = As[r * 132 + k];
    #pragma unroll
    for (int j = 0; j < 10; ++j) acc[j] = fmaf(a, Ws[k * 40 + cg + j], acc[j]);
  }
  int gr = row0 + r;
  if (gr < M) {
    #pragma unroll
    for (int j = 0; j < 10; ++j) Cb[(size_t)gr * 40 + cg + j] = f2bf(acc[j]);
  }
}

// ---------------------------------------------------------------------------
// Pull-SpMM over CSR: one wave per dst row, 128 cols (2/lane).
// ---------------------------------------------------------------------------
template <bool BF16>
__global__ __launch_bounds__(256) void spmm128_kernel(
    const int* __restrict__ row_ptr, const int2* __restrict__ edges,
    const void* __restrict__ Xv, float* __restrict__ Y,
    const float* __restrict__ bias, int nrows, int do_relu) {
  int wid = (blockIdx.x * 256 + threadIdx.x) >> 6;
  int lane = threadIdx.x & 63;
  if (wid >= nrows) return;
  int start = row_ptr[wid], end = row_ptr[wid + 1];
  float2 acc = make_float2(0.f, 0.f);
  for (int base = start; base < end; base += 64) {
    int cnt = end - base; if (cnt > 64) cnt = 64;
    int2 e_l = make_int2(0, 0);
    if (lane < cnt) e_l = edges[base + lane];
    for (int j = 0; j < cnt; ++j) {
      int src = __shfl(e_l.x, j);
      float val = __int_as_float(__shfl(e_l.y, j));
      float2 xv;
      if (BF16) {
        unsigned int u = *(const unsigned int*)
            ((const unsigned short*)Xv + (size_t)src * 128 + lane * 2);
        xv = make_float2(bf_lo(u), bf_hi(u));
      } else {
        xv = *(const float2*)((const float*)Xv + (size_t)src * 128 + lane * 2);
      }
      acc.x = fmaf(val, xv.x, acc.x);
      acc.y = fmaf(val, xv.y, acc.y);
    }
  }
  if (bias) { acc.x += bias[lane * 2]; acc.y += bias[lane * 2 + 1]; }
  if (do_relu) { acc.x = fmaxf(acc.x, 0.f); acc.y = fmaxf(acc.y, 0.f); }
  *(float2*)&Y[(size_t)wid * 128 + lane * 2] = acc;
}

// Pool (T-graph pull sum) fused with nwgt-embedding add:
// Hpool = sum_{src in bin} X[src];  H0 = Hpool + emb[nwgt[row]]  (fp32 + bf16)
__global__ __launch_bounds__(256) void pool_emb_kernel(
    const int* __restrict__ row_ptr, const int2* __restrict__ edges,
    const float* __restrict__ X, const int* __restrict__ nwgt,
    const float* __restrict__ emb, float* __restrict__ Hpool,
    float* __restrict__ H0, unsigned short* __restrict__ H0b, int nrows) {
  int wid = (blockIdx.x * 256 + threadIdx.x) >> 6;
  int lane = threadIdx.x & 63;
  if (wid >= nrows) return;
  int start = row_ptr[wid], end = row_ptr[wid + 1];
  float2 acc = make_float2(0.f, 0.f);
  for (int base = start; base < end; base += 64) {
    int cnt = end - base; if (cnt > 64) cnt = 64;
    int s_l = 0;
    if (lane < cnt) s_l = edges[base + lane].x;
    for (int j = 0; j < cnt; ++j) {
      int src = __shfl(s_l, j);
      float2 xv = *(const float2*)&X[(size_t)src * 128 + lane * 2];
      acc.x += xv.x;
      acc.y += xv.y;
    }
  }
  *(float2*)&Hpool[(size_t)wid * 128 + lane * 2] = acc;
  float2 ev = *(const float2*)&emb[(size_t)nwgt[wid] * 128 + lane * 2];
  float2 h0 = make_float2(acc.x + ev.x, acc.y + ev.y);
  *(float2*)&H0[(size_t)wid * 128 + lane * 2] = h0;
  unsigned int packed = ((unsigned int)f2bf(h0.x)) | (((unsigned int)f2bf(h0.y)) << 16);
  *(unsigned int*)(H0b + (size_t)wid * 128 + lane * 2) = packed;
}

__global__ __launch_bounds__(256) void spmm40_kernel(
    const int* __restrict__ row_ptr, const int2* __restrict__ edges,
    const unsigned short* __restrict__ Xb, float* __restrict__ Y,
    const float* __restrict__ bias, int nrows) {
  int wid = (blockIdx.x * 256 + threadIdx.x) >> 6;
  int lane = threadIdx.x & 63;
  if (wid >= nrows) return;
  int start = row_ptr[wid], end = row_ptr[wid + 1];
  float acc = 0.f;
  for (int base = start; base < end; base += 64) {
    int cnt = end - base; if (cnt > 64) cnt = 64;
    int2 e_l = make_int2(0, 0);
    if (lane < cnt) e_l = edges[base + lane];
    for (int j = 0; j < cnt; ++j) {
      int src = __shfl(e_l.x, j);
      float val = __int_as_float(__shfl(e_l.y, j));
      if (lane < 40) {
        unsigned short u = Xb[(size_t)src * 40 + lane];
        acc = fmaf(val, __uint_as_float(((unsigned int)u) << 16), acc);
      }
    }
  }
  if (lane < 40) Y[(size_t)wid * 40 + lane] = acc + bias[lane];
}

// ---------------------------------------------------------------------------
// Fused CRF row kernel: wave per dst row; q[row] in registers; per edge
// gather k[src] (bf16) -> butterfly dot -> logit; online-softmax rescale of
// running (z, msg) with h0[src] (bf16) gathered in the same pass.
// ---------------------------------------------------------------------------
__global__ __launch_bounds__(256) void crf_fused_kernel(
    const int* __restrict__ row_ptr, const int2* __restrict__ edges,
    const float* __restrict__ Q, const unsigned short* __restrict__ Kb,
    const float* __restrict__ H0, const unsigned short* __restrict__ H0b,
    float* __restrict__ Y, const float* __restrict__ alpha_p,
    const float* __restrict__ beta_p, int nrows) {
  int wid = (blockIdx.x * 256 + threadIdx.x) >> 6;
  int lane = threadIdx.x & 63;
  if (wid >= nrows) return;
  int start = row_ptr[wid], end = row_ptr[wid + 1];
  float2 qv = *(const float2*)&Q[(size_t)wid * 128 + lane * 2];
  float m = -3.4e38f, z = 0.f;
  float2 msg = make_float2(0.f, 0.f);
  for (int e = start; e < end; ++e) {
    int src = edges[e].x;
    unsigned int ku = *(const unsigned int*)(Kb + (size_t)src * 128 + lane * 2);
    float p = qv.x * bf_lo(ku) + qv.y * bf_hi(ku);
    #pragma unroll
    for (int d = 32; d >= 1; d >>= 1) p += __shfl_xor(p, d);
    p *= 0.08838834764831845f;  // 1/sqrt(128); identical across lanes
    float mn = fmaxf(m, p);
    float corr = __expf(m - mn);   // 0 when m==-inf (first edge)
    float w = __expf(p - mn);
    z = z * corr + w;
    unsigned int hu = *(const unsigned int*)(H0b + (size_t)src * 128 + lane * 2);
    msg.x = msg.x * corr + w * bf_lo(hu);
    msg.y = msg.y * corr + w * bf_hi(hu);
    m = mn;
  }
  float alpha = *alpha_p, beta = *beta_p;
  float inv = 1.0f / (z + 1e-16f);
  float2 h0i = *(const float2*)&H0[(size_t)wid * 128 + lane * 2];
  float sc = 1.0f / (alpha + beta);
  float2 o;
  o.x = (alpha * h0i.x + beta * (msg.x * inv)) * sc;
  o.y = (alpha * h0i.y + beta * (msg.y * inv)) * sc;
  *(float2*)&Y[(size_t)wid * 128 + lane * 2] = o;
}

// Fused double unpool: crf_h[r] = h2[assign1[assign0[r]]] + h1[assign0[r]] + gcn[r]
__global__ __launch_bounds__(256) void unpool2_kernel(
    const float* __restrict__ H2, const float* __restrict__ H1,
    const float* __restrict__ Gcn, const int* __restrict__ assign0,
    const int* __restrict__ assign1, float* __restrict__ Y, int nrows) {
  int wid = (blockIdx.x * 256 + threadIdx.x) >> 6;
  int lane = threadIdx.x & 63;
  if (wid >= nrows) return;
  int a0 = assign0[wid];
  int a1 = assign1[a0];
  float2 v2 = *(const float2*)&H2[(size_t)a1 * 128 + lane * 2];
  float2 v1 = *(const float2*)&H1[(size_t)a0 * 128 + lane * 2];
  float2 vg = *(const float2*)&Gcn[(size_t)wid * 128 + lane * 2];
  float2 o = make_float2(v2.x + v1.x + vg.x, v2.y + v1.y + vg.y);
  *(float2*)&Y[(size_t)wid * 128 + lane * 2] = o;
}

}  // namespace

// ---------------------------------------------------------------------------
extern "C" void kernel_launch(void* const* d_in, const int* in_sizes, int n_in,
                              void* d_out, int out_size, void* d_ws, size_t ws_size,
                              hipStream_t stream) {
  const float* x       = (const float*)d_in[0];
  const int*   A0_idx  = (const int*)d_in[1];
  const float* A0_val  = (const float*)d_in[2];
  const int*   A1_idx  = (const int*)d_in[3];
  const int*   A2_idx  = (const int*)d_in[5];
  const int*   assign0 = (const int*)d_in[7];
  const int*   assign1 = (const int*)d_in[8];
  const int*   nwgt1   = (const int*)d_in[9];
  const int*   nwgt2   = (const int*)d_in[10];
  const float* gc1_W   = (const float*)d_in[11];
  const float* gc1_b   = (const float*)d_in[12];
  const float* gc2_W   = (const float*)d_in[13];
  const float* gc2_b   = (const float*)d_in[14];
  const float* c1_Wq   = (const float*)d_in[15];
  const float* c1_Wk   = (const float*)d_in[16];
  const float* c1_emb  = (const float*)d_in[17];
  const float* c1_al   = (const float*)d_in[18];
  const float* c1_be   = (const float*)d_in[19];
  const float* c2_Wq   = (const float*)d_in[20];
  const float* c2_Wk   = (const float*)d_in[21];
  const float* c2_emb  = (const float*)d_in[22];
  const float* c2_al   = (const float*)d_in[23];
  const float* c2_be   = (const float*)d_in[24];

  float* out_g = (float*)d_out;                      // [N0, 40]
  float* gcn_h = out_g + (size_t)kN0 * 40;           // [N0, 128]
  float* crf_h = gcn_h + (size_t)kN0 * 128;          // [N0, 128]

  // ---- workspace carving ----
  char* ws = (char*)d_ws;
  size_t off = 0;
  auto carve = [&](size_t bytes) -> void* {
    void* p = ws + off;
    off += (bytes + 511) & ~(size_t)511;
    return p;
  };
  int*   counts   = (int*)carve((size_t)(kTB + 1) * 4);
  int*   row_ptr  = (int*)carve((size_t)(kTB + 1) * 4);
  int*   partials = (int*)carve(1024);
  int*   rank     = (int*)carve((size_t)kTE * 4);          // 8.9 MB
  int2*  edges    = (int2*)carve((size_t)kTE * 8);         // 17.8 MB
  float* h1_crf   = (float*)carve((size_t)kN1 * 128 * 4);  // 12.8 MB, long-lived
  char*  arena    = (char*)carve(51200000 + 4096);         // reused overlays
  // Overlays (byte offsets; lifetimes vs launch order):
  unsigned short* xWb   = (unsigned short*)(arena);              // [gc1 gemm .. gc1 spmm]
  float* h1_pool = (float*)(arena);                              // [pool1 .. qk1]
  float* h0_1    = (float*)(arena + 12800000);                   // [pool1 .. crf1]
  unsigned short* h0_1b = (unsigned short*)(arena + 25600000);   // [pool1 .. crf1]
  float* q1      = (float*)(arena + 32000000);                   // [qk1 .. crf1]
  unsigned short* k1b   = (unsigned short*)(arena + 44800000);   // [qk1 .. crf1]
  float* h2_pool = (float*)(arena);                              // [pool2 .. qk2]
  float* h0_2    = (float*)(arena + 3200000);                    // [pool2 .. crf2]
  unsigned short* h0_2b = (unsigned short*)(arena + 6400000);    // [pool2 .. crf2]
  float* q2      = (float*)(arena + 8000000);                    // [qk2 .. crf2]
  unsigned short* k2b   = (unsigned short*)(arena + 11200000);   // [qk2 .. crf2]
  float* h2_crf  = (float*)(arena + 12800000);                   // [crf2 .. unpool]
  unsigned short* hW2b  = (unsigned short*)(arena);              // [gemm40 .. spmm40]

  // ---- 1. batched CSR build for {A0, A1, A2, T0, T1} ----
  hipMemsetAsync(counts, 0, (size_t)(kTB + 1) * 4, stream);
  rank_kernel<<<(kTE + 255) / 256, 256, 0, stream>>>(A0_idx, A1_idx, A2_idx,
                                                     assign0, assign1, counts, rank);
  scan1_kernel<<<kNBLK, 256, 0, stream>>>(counts, row_ptr, partials, kTB);
  scan2_kernel<<<1, 256, 0, stream>>>(partials, kNBLK);
  scan3_kernel<<<(kTB + 255) / 256, 256, 0, stream>>>(row_ptr, partials, kTB, kTE);
  place_kernel<<<(kTE + 255) / 256, 256, 0, stream>>>(
      A0_idx, A0_val, A1_idx, A2_idx, assign0, assign1, row_ptr, rank, edges);

  // ---- 2. gc1: h = relu(A0 @ (x W1) + b1) -> gcn_hidden ----
  gemm128_kernel<<<(kN0 + 63) / 64, 256, 0, stream>>>(x, gc1_W, nullptr, xWb, kN0);
  spmm128_kernel<true><<<(kN0 + 3) / 4, 256, 0, stream>>>(row_ptr, edges, xWb,
                                                          gcn_h, gc1_b, kN0, 1);
  // ---- 3. level-1 pool(+emb) + QK + CRF ----
  pool_emb_kernel<<<(kN1 + 3) / 4, 256, 0, stream>>>(row_ptr + kBO3, edges, gcn_h,
                                                     nwgt1, c1_emb, h1_pool, h0_1,
                                                     h0_1b, kN1);
  gemm128_qk_kernel<<<(kN1 + 63) / 64, 256, 0, stream>>>(h1_pool, c1_Wq, c1_Wk,
                                                         q1, k1b, kN1);
  crf_fused_kernel<<<(kN1 + 3) / 4, 256, 0, stream>>>(row_ptr + kBO1, edges, q1, k1b,
                                                      h0_1, h0_1b, h1_crf, c1_al,
                                                      c1_be, kN1);
  // ---- 4. level-2 pool(+emb) + QK + CRF ----
  pool_emb_kernel<<<(kN2 + 3) / 4, 256, 0, stream>>>(row_ptr + kBO4, edges, h1_crf,
                                                     nwgt2, c2_emb, h2_pool, h0_2,
                                                     h0_2b, kN2);
  gemm128_qk_kernel<<<(kN2 + 63) / 64, 256, 0, stream>>>(h2_pool, c2_Wq, c2_Wk,
                                                         q2, k2b, kN2);
  crf_fused_kernel<<<(kN2 + 3) / 4, 256, 0, stream>>>(row_ptr + kBO2, edges, q2, k2b,
                                                      h0_2, h0_2b, h2_crf, c2_al,
                                                      c2_be, kN2);
  // ---- 5. fused double unpool with skips -> crf_hidden ----
  unpool2_kernel<<<(kN0 + 3) / 4, 256, 0, stream>>>(h2_crf, h1_crf, gcn_h,
                                                    assign0, assign1, crf_h, kN0);
  // ---- 6. gc2: out = A0 @ (crf_hidden W2) + b2 ----
  gemm40_kernel<<<(kN0 + 63) / 64, 256, 0, stream>>>(crf_h, gc2_W, hW2b, kN0);
  spmm40_kernel<<<(kN0 + 3) / 4, 256, 0, stream>>>(row_ptr, edges, hW2b,
                                                   out_g, gc2_b, kN0);
}

// Round 4
// 757.354 us; speedup vs baseline: 1.3636x; 1.1237x over previous
//
#include <hip/hip_runtime.h>
#include <hip/hip_bf16.h>
#include <math.h>

namespace {

constexpr int kN0 = 100000, kN1 = 25000, kN2 = 6250;
constexpr int kE0 = 1600000, kE1 = 400000, kE2 = 100000;
// Concatenated-edge layout: [A0 | A1 | A2 | T0(assign0) | T1(assign1)]
constexpr int kEO1 = kE0;                   // 1,600,000
constexpr int kEO2 = kEO1 + kE1;            // 2,000,000
constexpr int kEO3 = kEO2 + kE2;            // 2,100,000
constexpr int kEO4 = kEO3 + kN0;            // 2,200,000
constexpr int kTE  = kEO4 + kN1;            // 2,225,000
// Concatenated-bin layout (destination node counts per graph)
constexpr int kBO1 = kN0;                   // A1 bins
constexpr int kBO2 = kBO1 + kN1;            // A2 bins
constexpr int kBO3 = kBO2 + kN2;            // T0 bins
constexpr int kBO4 = kBO3 + kN1;            // T1 bins
constexpr int kTB  = kBO4 + kN2;            // 162,500
constexpr int kNBLK = (kTB + 1023) / 1024;  // 159 scan blocks

__device__ __forceinline__ float bf_lo(unsigned int u) {
  return __uint_as_float(u << 16);
}
__device__ __forceinline__ float bf_hi(unsigned int u) {
  return __uint_as_float(u & 0xffff0000u);
}
__device__ __forceinline__ unsigned short f2bf(float f) {
  __hip_bfloat16 h = __float2bfloat16(f);
  return *reinterpret_cast<unsigned short*>(&h);
}

// edge id -> (dst, boff) for rank; full decode for place
__device__ __forceinline__ void edge_bin(
    int t, const int* a0i, const int* a1i, const int* a2i,
    const int* as0, const int* as1, int& dst, int& boff) {
  if (t < kEO1)      { dst = a0i[t];        boff = 0;    }
  else if (t < kEO2) { dst = a1i[t - kEO1]; boff = kBO1; }
  else if (t < kEO3) { dst = a2i[t - kEO2]; boff = kBO2; }
  else if (t < kEO4) { dst = as0[t - kEO3]; boff = kBO3; }
  else               { dst = as1[t - kEO4]; boff = kBO4; }
}

__device__ __forceinline__ void edge_decode(
    int t, const int* a0i, const float* a0v, const int* a1i, const int* a2i,
    const int* as0, const int* as1, int& dst, int& src, int& boff, float& val) {
  if (t < kEO1)      { dst = a0i[t]; src = a0i[kE0 + t]; val = a0v[t]; boff = 0; }
  else if (t < kEO2) { int e = t - kEO1; dst = a1i[e]; src = a1i[kE1 + e]; val = 1.0f; boff = kBO1; }
  else if (t < kEO3) { int e = t - kEO2; dst = a2i[e]; src = a2i[kE2 + e]; val = 1.0f; boff = kBO2; }
  else if (t < kEO4) { int e = t - kEO3; dst = as0[e]; src = e;            val = 1.0f; boff = kBO3; }
  else               { int e = t - kEO4; dst = as1[e]; src = e;            val = 1.0f; boff = kBO4; }
}

// ---------------------------------------------------------------------------
// CSR build: rank (1 atomic pass, 4 edges/thread) -> scan -> place (no atomics)
// ---------------------------------------------------------------------------
constexpr int kRankT = (kTE + 3) / 4;  // threads; edge ids t, t+T, t+2T, t+3T

__global__ __launch_bounds__(256) void rank_kernel(
    const int* __restrict__ a0i, const int* __restrict__ a1i,
    const int* __restrict__ a2i, const int* __restrict__ as0,
    const int* __restrict__ as1, int* __restrict__ counts,
    int* __restrict__ rank) {
  int tid = blockIdx.x * 256 + threadIdx.x;
  if (tid >= kRankT) return;
  int r[4];
  #pragma unroll
  for (int i = 0; i < 4; ++i) {
    int t = tid + i * kRankT;
    if (t < kTE) {
      int dst, boff;
      edge_bin(t, a0i, a1i, a2i, as0, as1, dst, boff);
      r[i] = atomicAdd(&counts[boff + dst], 1);
    }
  }
  #pragma unroll
  for (int i = 0; i < 4; ++i) {
    int t = tid + i * kRankT;
    if (t < kTE) rank[t] = r[i];
  }
}

__global__ __launch_bounds__(256) void scan1_kernel(
    const int* __restrict__ in, int* __restrict__ out,
    int* __restrict__ partials, int n) {
  __shared__ int sdata[256];
  int t = threadIdx.x;
  int base = blockIdx.x * 1024;
  int v[4]; int s = 0;
  #pragma unroll
  for (int j = 0; j < 4; ++j) {
    int i = base + t * 4 + j;
    v[j] = (i < n) ? in[i] : 0;
    s += v[j];
  }
  sdata[t] = s;
  __syncthreads();
  for (int off = 1; off < 256; off <<= 1) {
    int x = (t >= off) ? sdata[t - off] : 0;
    __syncthreads();
    sdata[t] += x;
    __syncthreads();
  }
  int excl = sdata[t] - s;
  int run = 0;
  #pragma unroll
  for (int j = 0; j < 4; ++j) {
    int i = base + t * 4 + j;
    if (i < n) out[i] = excl + run;
    run += v[j];
  }
  if (t == 255) partials[blockIdx.x] = sdata[255];
}

__global__ __launch_bounds__(256) void scan2_kernel(int* partials, int nb) {
  __shared__ int sdata[256];
  int t = threadIdx.x;
  sdata[t] = (t < nb) ? partials[t] : 0;
  __syncthreads();
  for (int off = 1; off < 256; off <<= 1) {
    int x = (t >= off) ? sdata[t - off] : 0;
    __syncthreads();
    sdata[t] += x;
    __syncthreads();
  }
  if (t < nb) partials[t] = (t == 0) ? 0 : sdata[t - 1];
}

__global__ __launch_bounds__(256) void scan3_kernel(
    int* __restrict__ out, const int* __restrict__ partials, int n, int total) {
  int i = blockIdx.x * 256 + threadIdx.x;
  if (i < n) out[i] += partials[i >> 10];
  if (i == 0) out[n] = total;
}

__global__ __launch_bounds__(256) void place_kernel(
    const int* __restrict__ a0i, const float* __restrict__ a0v,
    const int* __restrict__ a1i, const int* __restrict__ a2i,
    const int* __restrict__ as0, const int* __restrict__ as1,
    const int* __restrict__ row_ptr, const int* __restrict__ rank,
    int2* __restrict__ edges) {
  int tid = blockIdx.x * 256 + threadIdx.x;
  if (tid >= kRankT) return;
  int pos[4]; int2 rec[4];
  #pragma unroll
  for (int i = 0; i < 4; ++i) {
    int t = tid + i * kRankT;
    if (t < kTE) {
      int dst, src, boff; float val;
      edge_decode(t, a0i, a0v, a1i, a2i, as0, as1, dst, src, boff, val);
      pos[i] = row_ptr[boff + dst] + rank[t];
      rec[i] = make_int2(src, __float_as_int(val));
    }
  }
  #pragma unroll
  for (int i = 0; i < 4; ++i) {
    int t = tid + i * kRankT;
    if (t < kTE) edges[pos[i]] = rec[i];
  }
}

// ---------------------------------------------------------------------------
// GEMM C[M,128] = A[M,128] @ W[128,128]; fp32 and/or bf16 outputs.
// ---------------------------------------------------------------------------
__global__ __launch_bounds__(256) void gemm128_kernel(
    const float* __restrict__ A, const float* __restrict__ W,
    float* __restrict__ Cf, unsigned short* __restrict__ Cb, int M) {
  __shared__ float As[64 * 132];
  int t = threadIdx.x;
  int row0 = blockIdx.x << 6;
  #pragma unroll
  for (int i = 0; i < 8; ++i) {
    int f = t + (i << 8);
    int r = f >> 5, c4 = (f & 31) << 2;
    int gr = row0 + r;
    float4 v = make_float4(0.f, 0.f, 0.f, 0.f);
    if (gr < M) v = *(const float4*)&A[(size_t)gr * 128 + c4];
    *(float4*)&As[r * 132 + c4] = v;
  }
  __syncthreads();
  int wcol = t & 31;
  int c4 = wcol << 2;
  int rsub = t >> 5;
  float4 acc[8];
  #pragma unroll
  for (int j = 0; j < 8; ++j) acc[j] = make_float4(0.f, 0.f, 0.f, 0.f);
  const float4* W4 = (const float4*)W;
  #pragma unroll 4
  for (int k = 0; k < 128; ++k) {
    float4 w = W4[k * 32 + wcol];
    #pragma unroll
    for (int j = 0; j < 8; ++j) {
      float a = As[(rsub + (j << 3)) * 132 + k];
      acc[j].x = fmaf(a, w.x, acc[j].x);
      acc[j].y = fmaf(a, w.y, acc[j].y);
      acc[j].z = fmaf(a, w.z, acc[j].z);
      acc[j].w = fmaf(a, w.w, acc[j].w);
    }
  }
  #pragma unroll
  for (int j = 0; j < 8; ++j) {
    int gr = row0 + rsub + (j << 3);
    if (gr < M) {
      if (Cf) *(float4*)&Cf[(size_t)gr * 128 + c4] = acc[j];
      if (Cb) {
        ushort4 b;
        b.x = f2bf(acc[j].x); b.y = f2bf(acc[j].y);
        b.z = f2bf(acc[j].z); b.w = f2bf(acc[j].w);
        *(ushort4*)&Cb[(size_t)gr * 128 + c4] = b;
      }
    }
  }
}

// Fused Q/K projection: one LDS tile of A, two K-loops (Wq -> fp32, Wk -> bf16).
__global__ __launch_bounds__(256) void gemm128_qk_kernel(
    const float* __restrict__ A, const float* __restrict__ Wq,
    const float* __restrict__ Wk, float* __restrict__ Qf,
    unsigned short* __restrict__ Kb, int M) {
  __shared__ float As[64 * 132];
  int t = threadIdx.x;
  int row0 = blockIdx.x << 6;
  #pragma unroll
  for (int i = 0; i < 8; ++i) {
    int f = t + (i << 8);
    int r = f >> 5, c4 = (f & 31) << 2;
    int gr = row0 + r;
    float4 v = make_float4(0.f, 0.f, 0.f, 0.f);
    if (gr < M) v = *(const float4*)&A[(size_t)gr * 128 + c4];
    *(float4*)&As[r * 132 + c4] = v;
  }
  __syncthreads();
  int wcol = t & 31;
  int c4 = wcol << 2;
  int rsub = t >> 5;
  float4 acc[8];
  const float4* Wq4 = (const float4*)Wq;
  const float4* Wk4 = (const float4*)Wk;
  #pragma unroll
  for (int j = 0; j < 8; ++j) acc[j] = make_float4(0.f, 0.f, 0.f, 0.f);
  #pragma unroll 4
  for (int k = 0; k < 128; ++k) {
    float4 w = Wq4[k * 32 + wcol];
    #pragma unroll
    for (int j = 0; j < 8; ++j) {
      float a = As[(rsub + (j << 3)) * 132 + k];
      acc[j].x = fmaf(a, w.x, acc[j].x);
      acc[j].y = fmaf(a, w.y, acc[j].y);
      acc[j].z = fmaf(a, w.z, acc[j].z);
      acc[j].w = fmaf(a, w.w, acc[j].w);
    }
  }
  #pragma unroll
  for (int j = 0; j < 8; ++j) {
    int gr = row0 + rsub + (j << 3);
    if (gr < M) *(float4*)&Qf[(size_t)gr * 128 + c4] = acc[j];
  }
  #pragma unroll
  for (int j = 0; j < 8; ++j) acc[j] = make_float4(0.f, 0.f, 0.f, 0.f);
  #pragma unroll 4
  for (int k = 0; k < 128; ++k) {
    float4 w = Wk4[k * 32 + wcol];
    #pragma unroll
    for (int j = 0; j < 8; ++j) {
      float a = As[(rsub + (j << 3)) * 132 + k];
      acc[j].x = fmaf(a, w.x, acc[j].x);
      acc[j].y = fmaf(a, w.y, acc[j].y);
      acc[j].z = fmaf(a, w.z, acc[j].z);
      acc[j].w = fmaf(a, w.w, acc[j].w);
    }
  }
  #pragma unroll
  for (int j = 0; j < 8; ++j) {
    int gr = row0 + rsub + (j << 3);
    if (gr < M) {
      ushort4 b;
      b.x = f2bf(acc[j].x); b.y = f2bf(acc[j].y);
      b.z = f2bf(acc[j].z); b.w = f2bf(acc[j].w);
      *(ushort4*)&Kb[(size_t)gr * 128 + c4] = b;
    }
  }
}

// C[M,40] = A[M,128] @ W[128,40], bf16 output (consumed by gathers only)
__global__ __launch_bounds__(256) void gemm40_kernel(
    const float* __restrict__ A, const float* __restrict__ W,
    unsigned short* __restrict__ Cb, int M) {
  __shared__ float Ws[128 * 40];
  __shared__ float As[64 * 132];
  int t = threadIdx.x;
  int row0 = blockIdx.x << 6;
  #pragma unroll
  for (int i = 0; i < 5; ++i)
    ((float4*)Ws)[t + i * 256] = ((const float4*)W)[t + i * 256];
  #pragma unroll
  for (int i = 0; i < 8; ++i) {
    int f = t + (i << 8);
    int r = f >> 5, c4 = (f & 31) << 2;
    int gr = row0 + r;
    float4 v = make_float4(0.f, 0.f, 0.f, 0.f);
    if (gr < M) v = *(const float4*)&A[(size_t)gr * 128 + c4];
    *(float4*)&As[r * 132 + c4] = v;
  }
  __syncthreads();
  int r = t >> 2;
  int cg = (t & 3) * 10;
  float acc[10];
  #pragma unroll
  for (int j = 0; j < 10; ++j) acc[j] = 0.f;
  for (int k = 0; k < 128; ++k) {
    float a = As[r * 132 + k];
    #pragma unroll
    for (int j = 0; j < 10; ++j) acc[j] = fmaf(a, Ws[k * 40 + cg + j], acc[j]);
  }
  int gr = row0 + r;
  if (gr < M) {
    #pragma unroll
    for (int j = 0; j < 10; ++j) Cb[(size_t)gr * 40 + cg + j] = f2bf(acc[j]);
  }
}

// ---------------------------------------------------------------------------
// Pull-SpMM over CSR: one wave per dst row, 128 cols (2/lane), 4-way MLP.
// ---------------------------------------------------------------------------
template <bool BF16>
__global__ __launch_bounds__(256) void spmm128_kernel(
    const int* __restrict__ row_ptr, const int2* __restrict__ edges,
    const void* __restrict__ Xv, float* __restrict__ Y,
    const float* __restrict__ bias, int nrows, int do_relu) {
  int wid = (blockIdx.x * 256 + threadIdx.x) >> 6;
  int lane = threadIdx.x & 63;
  if (wid >= nrows) return;
  int start = row_ptr[wid], end = row_ptr[wid + 1];
  const unsigned short* Xb = (const unsigned short*)Xv;
  const float* Xf = (const float*)Xv;
  float2 accA = make_float2(0.f, 0.f), accB = make_float2(0.f, 0.f);
  for (int base = start; base < end; base += 64) {
    int cnt = end - base; if (cnt > 64) cnt = 64;
    int2 e_l = make_int2(0, 0);
    if (lane < cnt) e_l = edges[base + lane];
    int j = 0;
    for (; j + 4 <= cnt; j += 4) {
      int s0 = __shfl(e_l.x, j + 0), s1 = __shfl(e_l.x, j + 1);
      int s2 = __shfl(e_l.x, j + 2), s3 = __shfl(e_l.x, j + 3);
      float v0 = __int_as_float(__shfl(e_l.y, j + 0));
      float v1 = __int_as_float(__shfl(e_l.y, j + 1));
      float v2 = __int_as_float(__shfl(e_l.y, j + 2));
      float v3 = __int_as_float(__shfl(e_l.y, j + 3));
      if (BF16) {
        unsigned int u0 = *(const unsigned int*)(Xb + (size_t)s0 * 128 + lane * 2);
        unsigned int u1 = *(const unsigned int*)(Xb + (size_t)s1 * 128 + lane * 2);
        unsigned int u2 = *(const unsigned int*)(Xb + (size_t)s2 * 128 + lane * 2);
        unsigned int u3 = *(const unsigned int*)(Xb + (size_t)s3 * 128 + lane * 2);
        accA.x = fmaf(v0, bf_lo(u0), accA.x); accA.y = fmaf(v0, bf_hi(u0), accA.y);
        accB.x = fmaf(v1, bf_lo(u1), accB.x); accB.y = fmaf(v1, bf_hi(u1), accB.y);
        accA.x = fmaf(v2, bf_lo(u2), accA.x); accA.y = fmaf(v2, bf_hi(u2), accA.y);
        accB.x = fmaf(v3, bf_lo(u3), accB.x); accB.y = fmaf(v3, bf_hi(u3), accB.y);
      } else {
        float2 x0 = *(const float2*)(Xf + (size_t)s0 * 128 + lane * 2);
        float2 x1 = *(const float2*)(Xf + (size_t)s1 * 128 + lane * 2);
        float2 x2 = *(const float2*)(Xf + (size_t)s2 * 128 + lane * 2);
        float2 x3 = *(const float2*)(Xf + (size_t)s3 * 128 + lane * 2);
        accA.x = fmaf(v0, x0.x, accA.x); accA.y = fmaf(v0, x0.y, accA.y);
        accB.x = fmaf(v1, x1.x, accB.x); accB.y = fmaf(v1, x1.y, accB.y);
        accA.x = fmaf(v2, x2.x, accA.x); accA.y = fmaf(v2, x2.y, accA.y);
        accB.x = fmaf(v3, x3.x, accB.x); accB.y = fmaf(v3, x3.y, accB.y);
      }
    }
    for (; j < cnt; ++j) {
      int src = __shfl(e_l.x, j);
      float val = __int_as_float(__shfl(e_l.y, j));
      if (BF16) {
        unsigned int u = *(const unsigned int*)(Xb + (size_t)src * 128 + lane * 2);
        accA.x = fmaf(val, bf_lo(u), accA.x);
        accA.y = fmaf(val, bf_hi(u), accA.y);
      } else {
        float2 xv = *(const float2*)(Xf + (size_t)src * 128 + lane * 2);
        accA.x = fmaf(val, xv.x, accA.x);
        accA.y = fmaf(val, xv.y, accA.y);
      }
    }
  }
  float2 acc = make_float2(accA.x + accB.x, accA.y + accB.y);
  if (bias) { acc.x += bias[lane * 2]; acc.y += bias[lane * 2 + 1]; }
  if (do_relu) { acc.x = fmaxf(acc.x, 0.f); acc.y = fmaxf(acc.y, 0.f); }
  *(float2*)&Y[(size_t)wid * 128 + lane * 2] = acc;
}

// Pool (T-graph pull sum) fused with nwgt-embedding add, 4-way MLP.
__global__ __launch_bounds__(256) void pool_emb_kernel(
    const int* __restrict__ row_ptr, const int2* __restrict__ edges,
    const float* __restrict__ X, const int* __restrict__ nwgt,
    const float* __restrict__ emb, float* __restrict__ Hpool,
    float* __restrict__ H0, unsigned short* __restrict__ H0b, int nrows) {
  int wid = (blockIdx.x * 256 + threadIdx.x) >> 6;
  int lane = threadIdx.x & 63;
  if (wid >= nrows) return;
  int start = row_ptr[wid], end = row_ptr[wid + 1];
  float2 accA = make_float2(0.f, 0.f), accB = make_float2(0.f, 0.f);
  for (int base = start; base < end; base += 64) {
    int cnt = end - base; if (cnt > 64) cnt = 64;
    int s_l = 0;
    if (lane < cnt) s_l = edges[base + lane].x;
    int j = 0;
    for (; j + 4 <= cnt; j += 4) {
      int s0 = __shfl(s_l, j + 0), s1 = __shfl(s_l, j + 1);
      int s2 = __shfl(s_l, j + 2), s3 = __shfl(s_l, j + 3);
      float2 x0 = *(const float2*)&X[(size_t)s0 * 128 + lane * 2];
      float2 x1 = *(const float2*)&X[(size_t)s1 * 128 + lane * 2];
      float2 x2 = *(const float2*)&X[(size_t)s2 * 128 + lane * 2];
      float2 x3 = *(const float2*)&X[(size_t)s3 * 128 + lane * 2];
      accA.x += x0.x + x2.x; accA.y += x0.y + x2.y;
      accB.x += x1.x + x3.x; accB.y += x1.y + x3.y;
    }
    for (; j < cnt; ++j) {
      int src = __shfl(s_l, j);
      float2 xv = *(const float2*)&X[(size_t)src * 128 + lane * 2];
      accA.x += xv.x; accA.y += xv.y;
    }
  }
  float2 acc = make_float2(accA.x + accB.x, accA.y + accB.y);
  *(float2*)&Hpool[(size_t)wid * 128 + lane * 2] = acc;
  float2 ev = *(const float2*)&emb[(size_t)nwgt[wid] * 128 + lane * 2];
  float2 h0 = make_float2(acc.x + ev.x, acc.y + ev.y);
  *(float2*)&H0[(size_t)wid * 128 + lane * 2] = h0;
  unsigned int packed = ((unsigned int)f2bf(h0.x)) | (((unsigned int)f2bf(h0.y)) << 16);
  *(unsigned int*)(H0b + (size_t)wid * 128 + lane * 2) = packed;
}

__global__ __launch_bounds__(256) void spmm40_kernel(
    const int* __restrict__ row_ptr, const int2* __restrict__ edges,
    const unsigned short* __restrict__ Xb, float* __restrict__ Y,
    const float* __restrict__ bias, int nrows) {
  int wid = (blockIdx.x * 256 + threadIdx.x) >> 6;
  int lane = threadIdx.x & 63;
  if (wid >= nrows) return;
  int start = row_ptr[wid], end = row_ptr[wid + 1];
  float accA = 0.f, accB = 0.f;
  for (int base = start; base < end; base += 64) {
    int cnt = end - base; if (cnt > 64) cnt = 64;
    int2 e_l = make_int2(0, 0);
    if (lane < cnt) e_l = edges[base + lane];
    int j = 0;
    for (; j + 4 <= cnt; j += 4) {
      int s0 = __shfl(e_l.x, j + 0), s1 = __shfl(e_l.x, j + 1);
      int s2 = __shfl(e_l.x, j + 2), s3 = __shfl(e_l.x, j + 3);
      float v0 = __int_as_float(__shfl(e_l.y, j + 0));
      float v1 = __int_as_float(__shfl(e_l.y, j + 1));
      float v2 = __int_as_float(__shfl(e_l.y, j + 2));
      float v3 = __int_as_float(__shfl(e_l.y, j + 3));
      if (lane < 40) {
        unsigned short u0 = Xb[(size_t)s0 * 40 + lane];
        unsigned short u1 = Xb[(size_t)s1 * 40 + lane];
        unsigned short u2 = Xb[(size_t)s2 * 40 + lane];
        unsigned short u3 = Xb[(size_t)s3 * 40 + lane];
        accA = fmaf(v0, __uint_as_float(((unsigned int)u0) << 16), accA);
        accB = fmaf(v1, __uint_as_float(((unsigned int)u1) << 16), accB);
        accA = fmaf(v2, __uint_as_float(((unsigned int)u2) << 16), accA);
        accB = fmaf(v3, __uint_as_float(((unsigned int)u3) << 16), accB);
      }
    }
    for (; j < cnt; ++j) {
      int src = __shfl(e_l.x, j);
      float val = __int_as_float(__shfl(e_l.y, j));
      if (lane < 40) {
        unsigned short u = Xb[(size_t)src * 40 + lane];
        accA = fmaf(val, __uint_as_float(((unsigned int)u) << 16), accA);
      }
    }
  }
  if (lane < 40) Y[(size_t)wid * 40 + lane] = accA + accB + bias[lane];
}

// ---------------------------------------------------------------------------
// Fused CRF row kernel, 4 edges per step: batched k/h0 gathers (8 loads in
// flight), 4 interleaved butterfly dot-reductions, one online-softmax update.
// ---------------------------------------------------------------------------
__global__ __launch_bounds__(256) void crf_fused_kernel(
    const int* __restrict__ row_ptr, const int2* __restrict__ edges,
    const float* __restrict__ Q, const unsigned short* __restrict__ Kb,
    const float* __restrict__ H0, const unsigned short* __restrict__ H0b,
    float* __restrict__ Y, const float* __restrict__ alpha_p,
    const float* __restrict__ beta_p, int nrows) {
  int wid = (blockIdx.x * 256 + threadIdx.x) >> 6;
  int lane = threadIdx.x & 63;
  if (wid >= nrows) return;
  int start = row_ptr[wid], end = row_ptr[wid + 1];
  float2 qv = *(const float2*)&Q[(size_t)wid * 128 + lane * 2];
  const float kScale = 0.08838834764831845f;  // 1/sqrt(128)
  float m = -3.4e38f, z = 0.f;
  float2 msg = make_float2(0.f, 0.f);
  for (int base = start; base < end; base += 64) {
    int cnt = end - base; if (cnt > 64) cnt = 64;
    int s_l = 0;
    if (lane < cnt) s_l = edges[base + lane].x;
    int j = 0;
    for (; j + 4 <= cnt; j += 4) {
      int s0 = __shfl(s_l, j + 0), s1 = __shfl(s_l, j + 1);
      int s2 = __shfl(s_l, j + 2), s3 = __shfl(s_l, j + 3);
      unsigned int k0 = *(const unsigned int*)(Kb + (size_t)s0 * 128 + lane * 2);
      unsigned int k1 = *(const unsigned int*)(Kb + (size_t)s1 * 128 + lane * 2);
      unsigned int k2 = *(const unsigned int*)(Kb + (size_t)s2 * 128 + lane * 2);
      unsigned int k3 = *(const unsigned int*)(Kb + (size_t)s3 * 128 + lane * 2);
      unsigned int h0 = *(const unsigned int*)(H0b + (size_t)s0 * 128 + lane * 2);
      unsigned int h1 = *(const unsigned int*)(H0b + (size_t)s1 * 128 + lane * 2);
      unsigned int h2 = *(const unsigned int*)(H0b + (size_t)s2 * 128 + lane * 2);
      unsigned int h3 = *(const unsigned int*)(H0b + (size_t)s3 * 128 + lane * 2);
      float p0 = qv.x * bf_lo(k0) + qv.y * bf_hi(k0);
      float p1 = qv.x * bf_lo(k1) + qv.y * bf_hi(k1);
      float p2 = qv.x * bf_lo(k2) + qv.y * bf_hi(k2);
      float p3 = qv.x * bf_lo(k3) + qv.y * bf_hi(k3);
      #pragma unroll
      for (int d = 32; d >= 1; d >>= 1) {
        p0 += __shfl_xor(p0, d);
        p1 += __shfl_xor(p1, d);
        p2 += __shfl_xor(p2, d);
        p3 += __shfl_xor(p3, d);
      }
      p0 *= kScale; p1 *= kScale; p2 *= kScale; p3 *= kScale;
      float pm = fmaxf(fmaxf(p0, p1), fmaxf(p2, p3));
      float mn = fmaxf(m, pm);
      float corr = __expf(m - mn);
      float w0 = __expf(p0 - mn), w1 = __expf(p1 - mn);
      float w2 = __expf(p2 - mn), w3 = __expf(p3 - mn);
      z = z * corr + (w0 + w1) + (w2 + w3);
      msg.x = msg.x * corr + w0 * bf_lo(h0) + w1 * bf_lo(h1)
                           + w2 * bf_lo(h2) + w3 * bf_lo(h3);
      msg.y = msg.y * corr + w0 * bf_hi(h0) + w1 * bf_hi(h1)
                           + w2 * bf_hi(h2) + w3 * bf_hi(h3);
      m = mn;
    }
    for (; j < cnt; ++j) {
      int src = __shfl(s_l, j);
      unsigned int ku = *(const unsigned int*)(Kb + (size_t)src * 128 + lane * 2);
      unsigned int hu = *(const unsigned int*)(H0b + (size_t)src * 128 + lane * 2);
      float p = qv.x * bf_lo(ku) + qv.y * bf_hi(ku);
      #pragma unroll
      for (int d = 32; d >= 1; d >>= 1) p += __shfl_xor(p, d);
      p *= kScale;
      float mn = fmaxf(m, p);
      float corr = __expf(m - mn);
      float w = __expf(p - mn);
      z = z * corr + w;
      msg.x = msg.x * corr + w * bf_lo(hu);
      msg.y = msg.y * corr + w * bf_hi(hu);
      m = mn;
    }
  }
  float alpha = *alpha_p, beta = *beta_p;
  float inv = 1.0f / (z + 1e-16f);
  float2 h0i = *(const float2*)&H0[(size_t)wid * 128 + lane * 2];
  float sc = 1.0f / (alpha + beta);
  float2 o;
  o.x = (alpha * h0i.x + beta * (msg.x * inv)) * sc;
  o.y = (alpha * h0i.y + beta * (msg.y * inv)) * sc;
  *(float2*)&Y[(size_t)wid * 128 + lane * 2] = o;
}

// Fused double unpool: crf_h[r] = h2[assign1[assign0[r]]] + h1[assign0[r]] + gcn[r]
__global__ __launch_bounds__(256) void unpool2_kernel(
    const float* __restrict__ H2, const float* __restrict__ H1,
    const float* __restrict__ Gcn, const int* __restrict__ assign0,
    const int* __restrict__ assign1, float* __restrict__ Y, int nrows) {
  int wid = (blockIdx.x * 256 + threadIdx.x) >> 6;
  int lane = threadIdx.x & 63;
  if (wid >= nrows) return;
  int a0 = assign0[wid];
  int a1 = assign1[a0];
  float2 v2 = *(const float2*)&H2[(size_t)a1 * 128 + lane * 2];
  float2 v1 = *(const float2*)&H1[(size_t)a0 * 128 + lane * 2];
  float2 vg = *(const float2*)&Gcn[(size_t)wid * 128 + lane * 2];
  float2 o = make_float2(v2.x + v1.x + vg.x, v2.y + v1.y + vg.y);
  *(float2*)&Y[(size_t)wid * 128 + lane * 2] = o;
}

}  // namespace

// ---------------------------------------------------------------------------
extern "C" void kernel_launch(void* const* d_in, const int* in_sizes, int n_in,
                              void* d_out, int out_size, void* d_ws, size_t ws_size,
                              hipStream_t stream) {
  const float* x       = (const float*)d_in[0];
  const int*   A0_idx  = (const int*)d_in[1];
  const float* A0_val  = (const float*)d_in[2];
  const int*   A1_idx  = (const int*)d_in[3];
  const int*   A2_idx  = (const int*)d_in[5];
  const int*   assign0 = (const int*)d_in[7];
  const int*   assign1 = (const int*)d_in[8];
  const int*   nwgt1   = (const int*)d_in[9];
  const int*   nwgt2   = (const int*)d_in[10];
  const float* gc1_W   = (const float*)d_in[11];
  const float* gc1_b   = (const float*)d_in[12];
  const float* gc2_W   = (const float*)d_in[13];
  const float* gc2_b   = (const float*)d_in[14];
  const float* c1_Wq   = (const float*)d_in[15];
  const float* c1_Wk   = (const float*)d_in[16];
  const float* c1_emb  = (const float*)d_in[17];
  const float* c1_al   = (const float*)d_in[18];
  const float* c1_be   = (const float*)d_in[19];
  const float* c2_Wq   = (const float*)d_in[20];
  const float* c2_Wk   = (const float*)d_in[21];
  const float* c2_emb  = (const float*)d_in[22];
  const float* c2_al   = (const float*)d_in[23];
  const float* c2_be   = (const float*)d_in[24];

  float* out_g = (float*)d_out;                      // [N0, 40]
  float* gcn_h = out_g + (size_t)kN0 * 40;           // [N0, 128]
  float* crf_h = gcn_h + (size_t)kN0 * 128;          // [N0, 128]

  // ---- workspace carving ----
  char* ws = (char*)d_ws;
  size_t off = 0;
  auto carve = [&](size_t bytes) -> void* {
    void* p = ws + off;
    off += (bytes + 511) & ~(size_t)511;
    return p;
  };
  int*   counts   = (int*)carve((size_t)(kTB + 1) * 4);
  int*   row_ptr  = (int*)carve((size_t)(kTB + 1) * 4);
  int*   partials = (int*)carve(1024);
  int*   rank     = (int*)carve((size_t)kTE * 4);          // 8.9 MB
  int2*  edges    = (int2*)carve((size_t)kTE * 8);         // 17.8 MB
  float* h1_crf   = (float*)carve((size_t)kN1 * 128 * 4);  // 12.8 MB, long-lived
  char*  arena    = (char*)carve(51200000 + 4096);         // reused overlays
  // Overlays (byte offsets; lifetimes vs launch order):
  unsigned short* xWb   = (unsigned short*)(arena);              // [gc1 gemm .. gc1 spmm]
  float* h1_pool = (float*)(arena);                              // [pool1 .. qk1]
  float* h0_1    = (float*)(arena + 12800000);                   // [pool1 .. crf1]
  unsigned short* h0_1b = (unsigned short*)(arena + 25600000);   // [pool1 .. crf1]
  float* q1      = (float*)(arena + 32000000);                   // [qk1 .. crf1]
  unsigned short* k1b   = (unsigned short*)(arena + 44800000);   // [qk1 .. crf1]
  float* h2_pool = (float*)(arena);                              // [pool2 .. qk2]
  float* h0_2    = (float*)(arena + 3200000);                    // [pool2 .. crf2]
  unsigned short* h0_2b = (unsigned short*)(arena + 6400000);    // [pool2 .. crf2]
  float* q2      = (float*)(arena + 8000000);                    // [qk2 .. crf2]
  unsigned short* k2b   = (unsigned short*)(arena + 11200000);   // [qk2 .. crf2]
  float* h2_crf  = (float*)(arena + 12800000);                   // [crf2 .. unpool]
  unsigned short* hW2b  = (unsigned short*)(arena);              // [gemm40 .. spmm40]

  // ---- 1. batched CSR build for {A0, A1, A2, T0, T1} ----
  hipMemsetAsync(counts, 0, (size_t)(kTB + 1) * 4, stream);
  rank_kernel<<<(kRankT + 255) / 256, 256, 0, stream>>>(A0_idx, A1_idx, A2_idx,
                                                        assign0, assign1, counts, rank);
  scan1_kernel<<<kNBLK, 256, 0, stream>>>(counts, row_ptr, partials, kTB);
  scan2_kernel<<<1, 256, 0, stream>>>(partials, kNBLK);
  scan3_kernel<<<(kTB + 255) / 256, 256, 0, stream>>>(row_ptr, partials, kTB, kTE);
  place_kernel<<<(kRankT + 255) / 256, 256, 0, stream>>>(
      A0_idx, A0_val, A1_idx, A2_idx, assign0, assign1, row_ptr, rank, edges);

  // ---- 2. gc1: h = relu(A0 @ (x W1) + b1) -> gcn_hidden ----
  gemm128_kernel<<<(kN0 + 63) / 64, 256, 0, stream>>>(x, gc1_W, nullptr, xWb, kN0);
  spmm128_kernel<true><<<(kN0 + 3) / 4, 256, 0, stream>>>(row_ptr, edges, xWb,
                                                          gcn_h, gc1_b, kN0, 1);
  // ---- 3. level-1 pool(+emb) + QK + CRF ----
  pool_emb_kernel<<<(kN1 + 3) / 4, 256, 0, stream>>>(row_ptr + kBO3, edges, gcn_h,
                                                     nwgt1, c1_emb, h1_pool, h0_1,
                                                     h0_1b, kN1);
  gemm128_qk_kernel<<<(kN1 + 63) / 64, 256, 0, stream>>>(h1_pool, c1_Wq, c1_Wk,
                                                         q1, k1b, kN1);
  crf_fused_kernel<<<(kN1 + 3) / 4, 256, 0, stream>>>(row_ptr + kBO1, edges, q1, k1b,
                                                      h0_1, h0_1b, h1_crf, c1_al,
                                                      c1_be, kN1);
  // ---- 4. level-2 pool(+emb) + QK + CRF ----
  pool_emb_kernel<<<(kN2 + 3) / 4, 256, 0, stream>>>(row_ptr + kBO4, edges, h1_crf,
                                                     nwgt2, c2_emb, h2_pool, h0_2,
                                                     h0_2b, kN2);
  gemm128_qk_kernel<<<(kN2 + 63) / 64, 256, 0, stream>>>(h2_pool, c2_Wq, c2_Wk,
                                                         q2, k2b, kN2);
  crf_fused_kernel<<<(kN2 + 3) / 4, 256, 0, stream>>>(row_ptr + kBO2, edges, q2, k2b,
                                                      h0_2, h0_2b, h2_crf, c2_al,
                                                      c2_be, kN2);
  // ---- 5. fused double unpool with skips -> crf_hidden ----
  unpool2_kernel<<<(kN0 + 3) / 4, 256, 0, stream>>>(h2_crf, h1_crf, gcn_h,
                                                    assign0, assign1, crf_h, kN0);
  // ---- 6. gc2: out = A0 @ (crf_hidden W2) + b2 ----
  gemm40_kernel<<<(kN0 + 63) / 64, 256, 0, stream>>>(crf_h, gc2_W, hW2b, kN0);
  spmm40_kernel<<<(kN0 + 3) / 4, 256, 0, stream>>>(row_ptr, edges, hW2b,
                                                   out_g, gc2_b, kN0);
}